// Round 13
// baseline (234.953 us; speedup 1.0000x reference)
//
#include <hip/hip_runtime.h>

typedef unsigned short u16;
typedef unsigned int u32;
typedef __attribute__((ext_vector_type(8))) short bf16x8;
typedef __attribute__((ext_vector_type(4))) float f32x4;

#define DEVI static __device__ __forceinline__

DEVI u16 f2b(float f){
  u32 x = __float_as_uint(f);
  return (u16)((x + 0x7fffu + ((x >> 16) & 1u)) >> 16);   // RNE bf16
}
DEVI float b2f(u16 u){ return __uint_as_float(((u32)u) << 16); }
DEVI float2 up2(u32 u){   // packed bf16 pair -> floats (low u16 = first elem)
  return make_float2(__uint_as_float(u << 16), __uint_as_float(u & 0xffff0000u));
}
DEVI void gload16(const u16* g, u16* l){
  __builtin_amdgcn_global_load_lds((const __attribute__((address_space(1))) void*)g,
                                   (__attribute__((address_space(3))) void*)l,
                                   16, 0, 0);
}

// qscale' = (1/sqrt(128)) * log2(e): scores land in base-2 units -> exp2f softmax
#define QSCALE 0.12751744900929456f

// ---------------- fused fp32 -> bf16 convert: x + all 8 weights (one launch) ----------------
struct CSrc { const float* s[9]; };
__global__ void cvt_all(CSrc cs, u16* __restrict__ xb, u16* __restrict__ wcat){
  int i = blockIdx.x * 256 + threadIdx.x;     // float4 index; 2097152 + 2162688 total
  if (i >= 4259840) return;
  const float4* s; int lo, di; uint2* d;
  if (i < 2097152){
    s = (const float4*)cs.s[0]; lo = 0; di = i; d = (uint2*)xb;
  } else {
    int j = i - 2097152; di = j; d = (uint2*)wcat;
    if      (j <  131072){ s = (const float4*)cs.s[1]; lo = 0;       }
    else if (j <  262144){ s = (const float4*)cs.s[2]; lo = 131072;  }
    else if (j <  786432){ s = (const float4*)cs.s[3]; lo = 262144;  }
    else if (j <  851968){ s = (const float4*)cs.s[4]; lo = 786432;  }
    else if (j <  917504){ s = (const float4*)cs.s[5]; lo = 851968;  }
    else if (j <  983040){ s = (const float4*)cs.s[6]; lo = 917504;  }
    else if (j < 1114112){ s = (const float4*)cs.s[7]; lo = 983040;  }
    else                 { s = (const float4*)cs.s[8]; lo = 1114112; }
  }
  float4 f = s[di - lo];
  u32 a = (u32)f2b(f.x) | ((u32)f2b(f.y) << 16);
  u32 b = (u32)f2b(f.z) | ((u32)f2b(f.w) << 16);
  d[di] = make_uint2(a, b);
}

// ---------------- big-K MFMA GEMM, 256x128 tile, BK=64, 8 waves (4Mx2N), phase-split ----------------
// C[M,N] = A[M,K] * W[N,K]^T.  MODE 0: bf16 row-major out   MODE 3: fp32 row-major out
// Triple-buffered LDS (144 KB), counted vmcnt(6) never-drain (flash-proven formula),
// 4 phases per K-tile: {8 ds_read + 1-2 gload(t+2) -> barrier -> lgkm0 -> 8 MFMA -> barrier}.
// LDS swizzle: 16B-granule g ^= row&7, pre-swizzled global source (both-sides involution).
template<int MODE>
__global__ __launch_bounds__(512, 1)
void gemm_big(const u16* __restrict__ A, int lda, const u16* __restrict__ W,
              void* __restrict__ D, int N, int K){
  __shared__ u16 A_s[3][256 * 64];   // 96 KB
  __shared__ u16 B_s[3][128 * 64];   // 48 KB
  const int tid = threadIdx.x;
  const int w = tid >> 6, l = tid & 63;
  const int lr = l & 15, hk = l >> 4;
  const int wm = w >> 1, wn = w & 1;          // 4M x 2N waves, 64x64 tile each
  int bid = blockIdx.y * gridDim.x + blockIdx.x;
  const int nwg = gridDim.x * gridDim.y;
  bid = (bid & 7) * (nwg >> 3) + (bid >> 3);  // XCD-contiguous remap (nwg % 8 == 0)
  const int bx = bid % gridDim.x, by = bid / gridDim.x;
  const int m0 = by * 256, n0 = bx * 128;
  const int nt = K >> 6;
  f32x4 acc[4][4] = {};

  auto STAGE_A = [&](int t, int s){           // sweep s in 0..3 (64 rows each)
    int row = s * 64 + w * 8 + (l >> 3);
    gload16(A + (size_t)(m0 + row) * lda + t * 64 + (((l & 7) ^ (row & 7)) << 3),
            &A_s[t % 3][s * 4096 + w * 512]);
  };
  auto STAGE_B = [&](int t, int s){           // sweep s in 0..1
    int row = s * 64 + w * 8 + (l >> 3);
    gload16(W + (size_t)(n0 + row) * K + t * 64 + (((l & 7) ^ (row & 7)) << 3),
            &B_s[t % 3][s * 4096 + w * 512]);
  };
  auto STAGE_ALL = [&](int t){
    STAGE_A(t, 0); STAGE_A(t, 1); STAGE_A(t, 2); STAGE_A(t, 3);
    STAGE_B(t, 0); STAGE_B(t, 1);
  };

  // prologue: tiles 0 and 1 issued; wait tile 0 only (tile 1 rides on).
  STAGE_ALL(0);
  STAGE_ALL(1);
  asm volatile("s_waitcnt vmcnt(6)" ::: "memory");
  __builtin_amdgcn_s_barrier();

  for (int t = 0; t < nt; ++t){
    const bool pre2 = (t + 2 < nt);
    const u16* As_ = A_s[t % 3];
    const u16* Bs_ = B_s[t % 3];
    #pragma unroll
    for (int ph = 0; ph < 4; ++ph){
      const int mq = ph >> 1, nq = ph & 1;    // C-quadrant of the 64x64 wave tile
      bf16x8 af[2][2], bf[2][2];
      #pragma unroll
      for (int i = 0; i < 2; ++i){
        int row = wm * 64 + (2 * mq + i) * 16 + lr;
        int rowb = wn * 64 + (2 * nq + i) * 16 + lr;
        #pragma unroll
        for (int kk = 0; kk < 2; ++kk){
          af[i][kk] = *(const bf16x8*)(As_ + row * 64 + (((kk * 4 + hk) ^ (row & 7)) << 3));
          bf[i][kk] = *(const bf16x8*)(Bs_ + rowb * 64 + (((kk * 4 + hk) ^ (rowb & 7)) << 3));
        }
      }
      if (pre2){
        if (ph == 0){ STAGE_A(t + 2, 0); STAGE_A(t + 2, 1); }
        else if (ph == 1){ STAGE_A(t + 2, 2); STAGE_A(t + 2, 3); }
        else if (ph == 2){ STAGE_B(t + 2, 0); }
        else            { STAGE_B(t + 2, 1); }
      }
      __builtin_amdgcn_s_barrier();
      asm volatile("s_waitcnt lgkmcnt(0)" ::: "memory");
      __builtin_amdgcn_sched_barrier(0);
      __builtin_amdgcn_s_setprio(1);
      #pragma unroll
      for (int i = 0; i < 2; ++i)
        #pragma unroll
        for (int j = 0; j < 2; ++j)
          #pragma unroll
          for (int kk = 0; kk < 2; ++kk)
            acc[2 * mq + i][2 * nq + j] =
              __builtin_amdgcn_mfma_f32_16x16x32_bf16(af[i][kk], bf[j][kk],
                                                      acc[2 * mq + i][2 * nq + j], 0, 0, 0);
      __builtin_amdgcn_s_setprio(0);
      if (ph == 3 && t + 1 < nt){
        // boundary: tile t+1's 6 loads are the oldest; keep t+2's 6 in flight.
        if (pre2) asm volatile("s_waitcnt vmcnt(6)" ::: "memory");
        else      asm volatile("s_waitcnt vmcnt(0)" ::: "memory");
      }
      __builtin_amdgcn_s_barrier();
    }
  }

  const int rb = (l >> 4) * 4, cl = l & 15;
  #pragma unroll
  for (int i = 0; i < 4; ++i){
    #pragma unroll
    for (int j = 0; j < 4; ++j){
      #pragma unroll
      for (int r = 0; r < 4; ++r){
        int m = m0 + wm * 64 + i * 16 + rb + r;
        int n = n0 + wn * 64 + j * 16 + cl;
        float v = acc[i][j][r];
        if (MODE == 0) ((u16*)D)[(size_t)m * N + n] = f2b(v);
        else           ((float*)D)[(size_t)m * N + n] = v;
      }
    }
  }
}

// ---------------- fused up-projections (K=256, lda=1536), one launch ----------------
// grid flat 1280 = 32 m-tiles x (16 q-side + 24 kv-side n-tiles), XCD-swizzled.
// q-side  (A=dcat+256): n<1024 -> qrp row-major ld1024; else q_c scatter *QSCALE.
// kv-side (A=dcat):     n<1024 -> k_c scatter; else V^T packed (B,NH,128,S).
__global__ __launch_bounds__(256, 2)
void gemm_up(const u16* __restrict__ dcat, const u16* __restrict__ qW,
             const u16* __restrict__ kvW, u16* __restrict__ qbuf,
             u16* __restrict__ qrp, u16* __restrict__ kbuf, u16* __restrict__ vt){
  __shared__ u16 As[128 * 32];
  __shared__ u16 Bs[128 * 32];
  const int tid = threadIdx.x;
  const int wave = tid >> 6, lane = tid & 63;
  const int lr = lane & 15, lk = lane >> 4;
  int bid = blockIdx.y * 40 + blockIdx.x;
  bid = (bid & 7) * 160 + (bid >> 3);                 // XCD-contiguous remap (1280/8)
  const int bx = bid % 40, by = bid / 40;
  const bool qside = bx < 16;
  const u16* A = qside ? dcat + 256 : dcat;
  const u16* W = qside ? qW : kvW;
  const int n0 = (qside ? bx : bx - 16) * 128;
  const int m0 = by * 128;
  const int wm = wave >> 1, wn = wave & 1;
  f32x4 acc[4][4] = {};

  const u16* a0 = A + (size_t)(m0 + (tid >> 2)) * 1536 + (tid & 3) * 8;
  const u16* a1 = a0 + (size_t)64 * 1536;
  const u16* b0 = W + (size_t)(n0 + (tid >> 2)) * 256 + (tid & 3) * 8;
  const u16* b1 = b0 + (size_t)64 * 256;
  u16* lA0 = As + wave * 512;  u16* lA1 = As + 2048 + wave * 512;
  u16* lB0 = Bs + wave * 512;  u16* lB1 = Bs + 2048 + wave * 512;

  for (int k0 = 0; k0 < 256; k0 += 32){
    __syncthreads();
    gload16(a0 + k0, lA0);
    gload16(a1 + k0, lA1);
    gload16(b0 + k0, lB0);
    gload16(b1 + k0, lB1);
    asm volatile("s_waitcnt vmcnt(0)" ::: "memory");
    __syncthreads();
    bf16x8 af[4], bfr[4];
    #pragma unroll
    for (int i = 0; i < 4; i++)
      af[i] = *(const bf16x8*)(As + (wm * 64 + i * 16 + lr) * 32 + lk * 8);
    #pragma unroll
    for (int j = 0; j < 4; j++)
      bfr[j] = *(const bf16x8*)(Bs + (wn * 64 + j * 16 + lr) * 32 + lk * 8);
    #pragma unroll
    for (int i = 0; i < 4; i++)
      #pragma unroll
      for (int j = 0; j < 4; j++)
        acc[i][j] = __builtin_amdgcn_mfma_f32_16x16x32_bf16(af[i], bfr[j], acc[i][j], 0, 0, 0);
  }

  const int rb = (lane >> 4) * 4, cl = lane & 15;
  #pragma unroll
  for (int i = 0; i < 4; i++){
    #pragma unroll
    for (int j = 0; j < 4; j++){
      const int mb = m0 + wm * 64 + i * 16 + rb;
      const int n  = n0 + wn * 64 + j * 16 + cl;
      if (!qside && n >= 1024){            // V^T packed x4 along s
        int n1 = n - 1024, h = n1 >> 7, d = n1 & 127, b = mb >> 11, s = mb & 2047;
        u32 lo = (u32)f2b(acc[i][j][0]) | ((u32)f2b(acc[i][j][1]) << 16);
        u32 hi = (u32)f2b(acc[i][j][2]) | ((u32)f2b(acc[i][j][3]) << 16);
        *(uint2*)(vt + (((size_t)(b * 16 + h) * 128 + d) * 2048 + s)) = make_uint2(lo, hi);
      } else {
        #pragma unroll
        for (int r = 0; r < 4; r++){
          int m = mb + r;
          float v = acc[i][j][r];
          if (qside){
            if (n < 1024){
              qrp[(size_t)m * 1024 + n] = f2b(v);
            } else {
              int n1 = n - 1024, h = n1 >> 6, d = n1 & 63;
              qbuf[(((size_t)(m >> 11) * 16 + h) * 2048 + (m & 2047)) * 128 + d] = f2b(v * QSCALE);
            }
          } else {                        // kv-side, n < 1024: k_c scatter
            int h = n >> 6, d = n & 63;
            kbuf[(((size_t)(m >> 11) * 16 + h) * 2048 + (m & 2047)) * 128 + d] = f2b(v);
          }
        }
      }
    }
  }
}

// ---------------- RoPE: rotate q_r/k_r halves into q/k dims [64,128) ----------------
__global__ void rope_k(const u16* __restrict__ qrp, const u16* __restrict__ dcat,
                       u16* __restrict__ Qb, u16* __restrict__ Kb){
  int idx = blockIdx.x * 256 + threadIdx.x;         // 2*2048*16*32 = 2^21
  if (idx >= (1 << 21)) return;
  int j = idx & 31, h = (idx >> 5) & 15, s = (idx >> 9) & 2047, b = (idx >> 20) & 1;
  float inv = exp2f((float)j * (-13.287712379549449f / 32.0f));
  float ang = (float)s * inv;
  float sn = sinf(ang), cs = cosf(ang);
  size_t soq = ((size_t)(b * 2048 + s)) * 1024 + h * 64 + j;
  size_t sok = ((size_t)(b * 2048 + s)) * 1536 + 512 + h * 64 + j;
  size_t dd = (((size_t)(b * 16 + h)) * 2048 + s) * 128;
  {
    float x1 = b2f(qrp[soq]), x2 = b2f(qrp[soq + 32]);
    Qb[dd + 64 + j] = f2b((x1 * cs - x2 * sn) * QSCALE);
    Qb[dd + 96 + j] = f2b((x1 * sn + x2 * cs) * QSCALE);
  }
  {
    float x1 = b2f(dcat[sok]), x2 = b2f(dcat[sok + 32]);
    Kb[dd + 64 + j] = f2b(x1 * cs - x2 * sn);
    Kb[dd + 96 + j] = f2b(x1 * sn + x2 * cs);
  }
}

// ---------------- flash partial: 8-wave QBLK=256, k-window split (z halves) ----------------
// grid (32 bh, 8 pp, 2 z); qt = 7-pp (heavy first). Block covers tiles [z*T, (z+1)*T),
// T = 2qt+2. Writes UNNORMALIZED O^T (bf16, token-major) + per-row (m,l) fp32.
__global__ __launch_bounds__(512, 1)
void flash_part(const u16* __restrict__ Q, const u16* __restrict__ K,
                const u16* __restrict__ VT, u16* __restrict__ Op0,
                u16* __restrict__ Op1, float2* __restrict__ ML){
  __shared__ u16 k_s[3][8192];   // [64 k][128 d] per buf, 256B rows, col16 ^= row&15
  __shared__ u16 v_s[8192];      // [128 d][64 k], 128B rows, col16 ^= d&7
  __shared__ u16 p_s[8][2048];   // per-wave [32 q][64 k], u16 ^= (q&7)<<3
  const int tid = threadIdx.x;
  const int w = tid >> 6, l = tid & 63;
  const int lr = l & 15, hk = l >> 4;
  const int bh = blockIdx.x;
  const int qt = 7 - blockIdx.y;
  const int z  = blockIdx.z;
  const int b = bh >> 4, h = bh & 15;
  const size_t base = (size_t)bh * 2048 * 128;
  const u16* Qb = Q + base;
  const u16* Kb = K + base;
  const u16* Vb = VT + base;
  u16* myp = p_s[w];
  const int q0 = qt * 256 + w * 32;
  const int T  = 2 * qt + 2;          // periods in this half-window
  const int t0 = z * T;               // absolute start tile

  bf16x8 qa[2][4];
  #pragma unroll
  for (int mi = 0; mi < 2; mi++)
    #pragma unroll
    for (int ks = 0; ks < 4; ks++)
      qa[mi][ks] = *(const bf16x8*)(Qb + (size_t)(q0 + mi * 16 + lr) * 128 + ks * 32 + hk * 8);

  f32x4 o[2][8] = {};                 // o[mi][dj][r] = O^T[d=dj*16+hk*4+r][q=q0+mi*16+lr]
  float mbase[2] = {-1e30f, -1e30f};
  float lsum[2] = {0.f, 0.f};

  auto STAGE_K = [&](int kt, int buf){
    #pragma unroll
    for (int it = 0; it < 2; ++it){
      int row = it * 32 + w * 4 + (l >> 4);
      gload16(Kb + (size_t)(kt * 64 + row) * 128 + (((l & 15) ^ (row & 15)) << 3),
              &k_s[buf][it * 4096 + w * 512]);
    }
  };
  auto STAGE_V = [&](int kt){
    #pragma unroll
    for (int it = 0; it < 2; ++it){
      int d = it * 64 + w * 8 + (l >> 3);
      gload16(Vb + (size_t)d * 2048 + kt * 64 + (((l & 7) ^ (d & 7)) << 3),
              &v_s[it * 4096 + w * 512]);
    }
  };

  // prologue: K(t0)->buf0, K(t0+1)->buf1; wait K(t0) only (K(t0+1) rides on).
  STAGE_K(t0, 0);
  STAGE_K(t0 + 1, 1);
  asm volatile("s_waitcnt vmcnt(2)" ::: "memory");
  __builtin_amdgcn_s_barrier();

  for (int tt = 0; tt < T; ++tt){
    const int t = t0 + tt;              // absolute tile
    STAGE_V(t);                         // issue V(t) first (FIFO age matters)
    const bool pre2 = (tt + 2 < T);
    if (pre2) STAGE_K(t + 2, (tt + 2) % 3);

    const bool act = (t * 64 <= q0 + 31);
    if (act){
      const u16* ks_ = k_s[tt % 3];
      // ---- S^T = K Q^T (64 k-rows x 32 q-cols per wave) ----
      f32x4 sc[2][4] = {};
      #pragma unroll
      for (int ksd = 0; ksd < 4; ++ksd){
        bf16x8 kb[4];
        #pragma unroll
        for (int nj = 0; nj < 4; ++nj){
          int row = nj * 16 + lr;
          kb[nj] = *(const bf16x8*)(ks_ + row * 128 + (((ksd * 4 + hk) ^ lr) << 3));
        }
        __builtin_amdgcn_s_setprio(1);
        #pragma unroll
        for (int mi = 0; mi < 2; ++mi)
          #pragma unroll
          for (int nj = 0; nj < 4; ++nj)
            sc[mi][nj] = __builtin_amdgcn_mfma_f32_16x16x32_bf16(kb[nj], qa[mi][ksd], sc[mi][nj], 0, 0, 0);
        __builtin_amdgcn_s_setprio(0);
      }
      // ---- mask (diagonal tiles only) + lane-local max ----
      float lmax[2] = {-3e38f, -3e38f};
      if (t * 64 + 63 > q0){
        #pragma unroll
        for (int mi = 0; mi < 2; ++mi){
          int qrow = q0 + mi * 16 + lr;
          #pragma unroll
          for (int nj = 0; nj < 4; ++nj)
            #pragma unroll
            for (int r = 0; r < 4; ++r){
              int kc = t * 64 + nj * 16 + hk * 4 + r;
              float s = (kc <= qrow) ? sc[mi][nj][r] : -1e30f;
              sc[mi][nj][r] = s;
              lmax[mi] = fmaxf(lmax[mi], s);
            }
        }
      } else {
        #pragma unroll
        for (int mi = 0; mi < 2; ++mi)
          #pragma unroll
          for (int nj = 0; nj < 4; ++nj)
            #pragma unroll
            for (int r = 0; r < 4; ++r)
              lmax[mi] = fmaxf(lmax[mi], sc[mi][nj][r]);
      }
      // ---- unconditional online rescale (base-2) ----
      #pragma unroll
      for (int mi = 0; mi < 2; ++mi){
        float mx = lmax[mi];
        mx = fmaxf(mx, __shfl_xor(mx, 16));
        mx = fmaxf(mx, __shfl_xor(mx, 32));
        float mnew = fmaxf(mbase[mi], mx);
        float alpha = exp2f(mbase[mi] - mnew);
        mbase[mi] = mnew;
        lsum[mi] *= alpha;
        #pragma unroll
        for (int dj = 0; dj < 8; ++dj)
          #pragma unroll
          for (int r = 0; r < 4; ++r) o[mi][dj][r] *= alpha;
      }
      // ---- P = exp2(S - base): lane-local sum, f2b packed writes ----
      #pragma unroll
      for (int mi = 0; mi < 2; ++mi){
        u16* prow = myp + (mi * 16 + lr) * 64;
        float rs = 0.f;
        #pragma unroll
        for (int nj = 0; nj < 4; ++nj){
          float p0 = exp2f(sc[mi][nj][0] - mbase[mi]);
          float p1 = exp2f(sc[mi][nj][1] - mbase[mi]);
          float p2 = exp2f(sc[mi][nj][2] - mbase[mi]);
          float p3 = exp2f(sc[mi][nj][3] - mbase[mi]);
          rs += (p0 + p1) + (p2 + p3);
          u32 a = (u32)f2b(p0) | ((u32)f2b(p1) << 16);
          u32 c = (u32)f2b(p2) | ((u32)f2b(p3) << 16);
          *(uint2*)(prow + ((nj * 16 + hk * 4) ^ ((lr & 7) << 3))) = make_uint2(a, c);
        }
        lsum[mi] += rs;
      }
    }

    // ---- counted wait: V(t) + K(t+1) landed; K(t+2) stays in flight across barriers ----
    if (pre2) asm volatile("s_waitcnt vmcnt(2)" ::: "memory");
    else      asm volatile("s_waitcnt vmcnt(0)" ::: "memory");
    __builtin_amdgcn_s_barrier();
    asm volatile("s_waitcnt lgkmcnt(0)" ::: "memory");   // own P writes visible
    __builtin_amdgcn_sched_barrier(0);

    if (act){
      // ---- O^T += V^T P^T ----
      #pragma unroll
      for (int kk = 0; kk < 2; ++kk){
        bf16x8 pb[2], va[8];
        #pragma unroll
        for (int mi = 0; mi < 2; ++mi)
          pb[mi] = *(const bf16x8*)(myp + (mi * 16 + lr) * 64 +
                     ((kk * 32 + hk * 8) ^ ((lr & 7) << 3)));
        #pragma unroll
        for (int dj = 0; dj < 8; ++dj){
          int d = dj * 16 + lr;
          va[dj] = *(const bf16x8*)(&v_s[d * 64 + (((kk * 4 + hk) ^ (lr & 7)) << 3)]);
        }
        __builtin_amdgcn_s_setprio(1);
        #pragma unroll
        for (int mi = 0; mi < 2; ++mi)
          #pragma unroll
          for (int dj = 0; dj < 8; ++dj)
            o[mi][dj] = __builtin_amdgcn_mfma_f32_16x16x32_bf16(va[dj], pb[mi], o[mi][dj], 0, 0, 0);
        __builtin_amdgcn_s_setprio(0);
      }
    }

    __builtin_amdgcn_s_barrier();    // all PV reads of v_s done before next STAGE_V
  }

  // ---- epilogue: reduce l across hk; store (m,l); write UNNORMALIZED O^T partial ----
  u16* Op = z ? Op1 : Op0;
  u16* scr = myp;                    // 16 q x 128 d per mi round (4 KB, wave-private)
  #pragma unroll
  for (int mi = 0; mi < 2; ++mi){
    float lt = lsum[mi];
    lt += __shfl_xor(lt, 16);
    lt += __shfl_xor(lt, 32);
    if (hk == 0){
      float2 v; v.x = mbase[mi]; v.y = lt;
      ML[((size_t)z * 32 + bh) * 2048 + qt * 256 + w * 32 + mi * 16 + lr] = v;
    }
    #pragma unroll
    for (int dj = 0; dj < 8; ++dj){
      u32 a = (u32)f2b(o[mi][dj][0]) | ((u32)f2b(o[mi][dj][1]) << 16);
      u32 c = (u32)f2b(o[mi][dj][2]) | ((u32)f2b(o[mi][dj][3]) << 16);
      *(uint2*)(scr + lr * 128 + ((dj * 16 + hk * 4) ^ ((lr & 7) << 3))) = make_uint2(a, c);
    }
    asm volatile("s_waitcnt lgkmcnt(0)" ::: "memory");
    __builtin_amdgcn_sched_barrier(0);
    #pragma unroll
    for (int rr = 0; rr < 4; ++rr){
      int row = rr * 4 + hk;
      uint4 vv = *(const uint4*)(scr + row * 128 + ((lr * 8) ^ ((row & 7) << 3)));
      *(uint4*)(Op + ((size_t)(b * 2048) + qt * 256 + w * 32 + mi * 16 + row) * 2048
                    + h * 128 + lr * 8) = vv;
    }
    asm volatile("s_waitcnt lgkmcnt(0)" ::: "memory");   // reads done before next mi overwrite
    __builtin_amdgcn_sched_barrier(0);
  }
}

// ---------------- merge two k-halves: O = (O0*w0 + O1*w1) / (l0*w0 + l1*w1) ----------------
__global__ void merge_k(const u16* __restrict__ Op0, const u16* __restrict__ Op1,
                        const float2* __restrict__ ML, u16* __restrict__ Y){
  int i = blockIdx.x * 256 + threadIdx.x;      // 8 cols per thread: 4096*2048/8 = 2^20
  if (i >= (1 << 20)) return;
  int row = i >> 8;                            // token row (b*2048+s)
  int c8 = (i & 255) << 3;                     // col group
  int b = row >> 11, s = row & 2047, h = c8 >> 7;
  int bh = b * 16 + h;
  float2 ml0 = ML[(size_t)bh * 2048 + s];
  float2 ml1 = ML[(size_t)(32 + bh) * 2048 + s];
  float m = fmaxf(ml0.x, ml1.x);
  float w0 = exp2f(ml0.x - m), w1 = exp2f(ml1.x - m);
  float inv = 1.0f / fmaxf(ml0.y * w0 + ml1.y * w1, 1e-30f);
  size_t off = (size_t)row * 2048 + c8;
  uint4 a = *(const uint4*)(Op0 + off);
  uint4 c = *(const uint4*)(Op1 + off);
  u32 res[4];
  u32 au[4] = {a.x, a.y, a.z, a.w};
  u32 cu[4] = {c.x, c.y, c.z, c.w};
  #pragma unroll
  for (int j = 0; j < 4; ++j){
    float2 f = up2(au[j]), g = up2(cu[j]);
    float r0 = (f.x * w0 + g.x * w1) * inv;
    float r1 = (f.y * w0 + g.y * w1) * inv;
    res[j] = (u32)f2b(r0) | ((u32)f2b(r1) << 16);
  }
  *(uint4*)(Y + off) = make_uint4(res[0], res[1], res[2], res[3]);
}

// ---------------------------------------------------------------------------
extern "C" void kernel_launch(void* const* d_in, const int* in_sizes, int n_in,
                              void* d_out, int out_size, void* d_ws, size_t ws_size,
                              hipStream_t stream){
  u16* p = (u16*)d_ws;
  auto alloc = [&](size_t n){ u16* r = p; p += n; return r; };
  // contiguous bf16 weights: [W_kv_d | W_q_d | W_rope_k | W_rope_q | W_q_u | W_k_u | W_v_u | W_o]
  u16* wcat = alloc(8650752);
  u16* downW  = wcat;                 // 1536 x 2048
  u16* qcatW  = wcat + 3145728;       // 2048 x 256 (rope_q, q_u)
  u16* kvcatW = wcat + 3670016;       // 3072 x 256 (k_u, v_u)
  u16* wo     = wcat + 4456448;       // 2048 x 2048
  u16* xb   = alloc(8388608);         // (4096, 2048) bf16; REUSED as Opart0 after rope
  u16* dcat = alloc(6291456);         // (4096, 1536); dcat+qrp REUSED as Opart1 after rope
  u16* qrp  = alloc(4194304);         // (4096, 1024) q_r pre-rope
  u16* qbuf = alloc(8388608);         // (B,NH,S,128)
  u16* kbuf = alloc(8388608);
  u16* vt   = alloc(8388608);         // (B,NH,128,S)
  u16* ybuf = alloc(8388608);         // (4096, 2048)
  float2* ml = (float2*)alloc(524288);  // [2][32][2048] (m,l) = 1 MiB

  CSrc cs;
  cs.s[0] = (const float*)d_in[0];   // x
  cs.s[1] = (const float*)d_in[1];   // W_kv_d
  cs.s[2] = (const float*)d_in[2];   // W_q_d
  cs.s[3] = (const float*)d_in[6];   // W_rope_k
  cs.s[4] = (const float*)d_in[7];   // W_rope_q
  cs.s[5] = (const float*)d_in[4];   // W_q_u
  cs.s[6] = (const float*)d_in[3];   // W_k_u
  cs.s[7] = (const float*)d_in[5];   // W_v_u
  cs.s[8] = (const float*)d_in[8];   // W_o
  cvt_all<<<16640, 256, 0, stream>>>(cs, xb, wcat);

  // down-projections fused: dcat = x @ [W_kv_d|W_q_d|W_rope_k]^T
  // 256x128 tiles: grid (1536/128=12, 4096/256=16) = 192 blocks (XCD-swizzled)
  gemm_big<0><<<dim3(12, 16), dim3(512), 0, stream>>>(xb, 2048, downW, dcat, 1536, 2048);
  // up-projections fused (q-side + kv-side), 1280 blocks, swizzled
  gemm_up<<<dim3(40, 32), dim3(256), 0, stream>>>(dcat, qcatW, kvcatW, qbuf, qrp, kbuf, vt);
  // rope into q/k dims [64,128) (q pre-scaled by QSCALE incl. log2e)
  rope_k<<<(1 << 21) / 256, 256, 0, stream>>>(qrp, dcat, qbuf, kbuf);
  // attention partials: xb/dcat/qrp are dead -> reuse as partial-O buffers
  u16* op0 = xb;                      // 8388608 u16 = one full (4096,2048) bf16
  u16* op1 = dcat;                    // dcat+qrp contiguous = 10485760 u16 >= 8388608
  flash_part<<<dim3(32, 8, 2), dim3(512), 0, stream>>>(qbuf, kbuf, vt, op0, op1, ml);
  // merge halves -> ybuf
  merge_k<<<4096, 256, 0, stream>>>(op0, op1, ml, ybuf);
  // output projection (fp32 out): grid (2048/128=16, 4096/256=16) = 256 blocks
  gemm_big<3><<<dim3(16, 16), dim3(512), 0, stream>>>(ybuf, 2048, wo, d_out, 2048, 2048);
}

// Round 14
// 213.962 us; speedup vs baseline: 1.0981x; 1.0981x over previous
//
#include <hip/hip_runtime.h>

typedef unsigned short u16;
typedef unsigned int u32;
typedef __attribute__((ext_vector_type(8))) short bf16x8;
typedef __attribute__((ext_vector_type(4))) float f32x4;

#define DEVI static __device__ __forceinline__

DEVI u16 f2b(float f){
  u32 x = __float_as_uint(f);
  return (u16)((x + 0x7fffu + ((x >> 16) & 1u)) >> 16);   // RNE bf16
}
DEVI float b2f(u16 u){ return __uint_as_float(((u32)u) << 16); }
DEVI float2 up2(u32 u){   // packed bf16 pair -> floats (low u16 = first elem)
  return make_float2(__uint_as_float(u << 16), __uint_as_float(u & 0xffff0000u));
}
DEVI void gload16(const u16* g, u16* l){
  __builtin_amdgcn_global_load_lds((const __attribute__((address_space(1))) void*)g,
                                   (__attribute__((address_space(3))) void*)l,
                                   16, 0, 0);
}

// qscale' = (1/sqrt(128)) * log2(e): scores land in base-2 units -> exp2f softmax
#define QSCALE 0.12751744900929456f

// ---------------- fused fp32 -> bf16 convert: x + all 8 weights (one launch) ----------------
struct CSrc { const float* s[9]; };
__global__ void cvt_all(CSrc cs, u16* __restrict__ xb, u16* __restrict__ wcat){
  int i = blockIdx.x * 256 + threadIdx.x;     // float4 index; 2097152 + 2162688 total
  if (i >= 4259840) return;
  const float4* s; int lo, di; uint2* d;
  if (i < 2097152){
    s = (const float4*)cs.s[0]; lo = 0; di = i; d = (uint2*)xb;
  } else {
    int j = i - 2097152; di = j; d = (uint2*)wcat;
    if      (j <  131072){ s = (const float4*)cs.s[1]; lo = 0;       }
    else if (j <  262144){ s = (const float4*)cs.s[2]; lo = 131072;  }
    else if (j <  786432){ s = (const float4*)cs.s[3]; lo = 262144;  }
    else if (j <  851968){ s = (const float4*)cs.s[4]; lo = 786432;  }
    else if (j <  917504){ s = (const float4*)cs.s[5]; lo = 851968;  }
    else if (j <  983040){ s = (const float4*)cs.s[6]; lo = 917504;  }
    else if (j < 1114112){ s = (const float4*)cs.s[7]; lo = 983040;  }
    else                 { s = (const float4*)cs.s[8]; lo = 1114112; }
  }
  float4 f = s[di - lo];
  u32 a = (u32)f2b(f.x) | ((u32)f2b(f.y) << 16);
  u32 b = (u32)f2b(f.z) | ((u32)f2b(f.w) << 16);
  d[di] = make_uint2(a, b);
}

// ---------------- MFMA bf16 GEMM:  C[M,N] = A[M,K] * W[N,K]^T ----------------
// MODE 0: bf16 row-major ld=N     MODE 3: fp32 row-major
// XCD swizzle: flat bid remap (nwg % 8 == 0 required — all our grids satisfy).
template<int MODE>
__global__ __launch_bounds__(256, 2)
void gemm_bt(const u16* __restrict__ A, int lda, const u16* __restrict__ W,
             void* __restrict__ D, int N, int K){
  __shared__ u16 As[128 * 32];
  __shared__ u16 Bs[128 * 32];
  const int tid = threadIdx.x;
  const int wave = tid >> 6, lane = tid & 63;
  const int lr = lane & 15, lk = lane >> 4;
  int bid = blockIdx.y * gridDim.x + blockIdx.x;
  const int nwg = gridDim.x * gridDim.y;
  bid = (bid & 7) * (nwg >> 3) + (bid >> 3);          // XCD-contiguous remap
  const int bx = bid % gridDim.x, by = bid / gridDim.x;
  const int m0 = by * 128, n0 = bx * 128;
  const int wm = wave >> 1, wn = wave & 1;
  f32x4 acc[4][4] = {};

  const u16* a0 = A + (size_t)(m0 + (tid >> 2)) * lda + (tid & 3) * 8;
  const u16* a1 = a0 + (size_t)64 * lda;
  const u16* b0 = W + (size_t)(n0 + (tid >> 2)) * K + (tid & 3) * 8;
  const u16* b1 = b0 + (size_t)64 * K;
  u16* lA0 = As + wave * 512;  u16* lA1 = As + 2048 + wave * 512;
  u16* lB0 = Bs + wave * 512;  u16* lB1 = Bs + 2048 + wave * 512;

  for (int k0 = 0; k0 < K; k0 += 32){
    __syncthreads();
    gload16(a0 + k0, lA0);
    gload16(a1 + k0, lA1);
    gload16(b0 + k0, lB0);
    gload16(b1 + k0, lB1);
    asm volatile("s_waitcnt vmcnt(0)" ::: "memory");
    __syncthreads();
    bf16x8 af[4], bfr[4];
    #pragma unroll
    for (int i = 0; i < 4; i++)
      af[i] = *(const bf16x8*)(As + (wm * 64 + i * 16 + lr) * 32 + lk * 8);
    #pragma unroll
    for (int j = 0; j < 4; j++)
      bfr[j] = *(const bf16x8*)(Bs + (wn * 64 + j * 16 + lr) * 32 + lk * 8);
    #pragma unroll
    for (int i = 0; i < 4; i++)
      #pragma unroll
      for (int j = 0; j < 4; j++)
        acc[i][j] = __builtin_amdgcn_mfma_f32_16x16x32_bf16(af[i], bfr[j], acc[i][j], 0, 0, 0);
  }

  const int rb = (lane >> 4) * 4, cl = lane & 15;
  #pragma unroll
  for (int i = 0; i < 4; i++){
    #pragma unroll
    for (int j = 0; j < 4; j++){
      const int mb = m0 + wm * 64 + i * 16 + rb;
      const int n  = n0 + wn * 64 + j * 16 + cl;
      #pragma unroll
      for (int r = 0; r < 4; r++){
        int m = mb + r;
        float v = acc[i][j][r];
        if (MODE == 0) ((u16*)D)[(size_t)m * N + n] = f2b(v);
        else           ((float*)D)[(size_t)m * N + n] = v;
      }
    }
  }
}

// ---------------- fused up-projections (K=256, lda=1536), one launch ----------------
// grid flat 1280 = 32 m-tiles x (16 q-side + 24 kv-side n-tiles), XCD-swizzled.
// q-side  (A=dcat+256): n<1024 -> qrp row-major ld1024; else q_c scatter *QSCALE.
// kv-side (A=dcat):     n<1024 -> k_c scatter; else V^T packed (B,NH,128,S).
__global__ __launch_bounds__(256, 2)
void gemm_up(const u16* __restrict__ dcat, const u16* __restrict__ qW,
             const u16* __restrict__ kvW, u16* __restrict__ qbuf,
             u16* __restrict__ qrp, u16* __restrict__ kbuf, u16* __restrict__ vt){
  __shared__ u16 As[128 * 32];
  __shared__ u16 Bs[128 * 32];
  const int tid = threadIdx.x;
  const int wave = tid >> 6, lane = tid & 63;
  const int lr = lane & 15, lk = lane >> 4;
  int bid = blockIdx.y * 40 + blockIdx.x;
  bid = (bid & 7) * 160 + (bid >> 3);                 // XCD-contiguous remap (1280/8)
  const int bx = bid % 40, by = bid / 40;
  const bool qside = bx < 16;
  const u16* A = qside ? dcat + 256 : dcat;
  const u16* W = qside ? qW : kvW;
  const int n0 = (qside ? bx : bx - 16) * 128;
  const int m0 = by * 128;
  const int wm = wave >> 1, wn = wave & 1;
  f32x4 acc[4][4] = {};

  const u16* a0 = A + (size_t)(m0 + (tid >> 2)) * 1536 + (tid & 3) * 8;
  const u16* a1 = a0 + (size_t)64 * 1536;
  const u16* b0 = W + (size_t)(n0 + (tid >> 2)) * 256 + (tid & 3) * 8;
  const u16* b1 = b0 + (size_t)64 * 256;
  u16* lA0 = As + wave * 512;  u16* lA1 = As + 2048 + wave * 512;
  u16* lB0 = Bs + wave * 512;  u16* lB1 = Bs + 2048 + wave * 512;

  for (int k0 = 0; k0 < 256; k0 += 32){
    __syncthreads();
    gload16(a0 + k0, lA0);
    gload16(a1 + k0, lA1);
    gload16(b0 + k0, lB0);
    gload16(b1 + k0, lB1);
    asm volatile("s_waitcnt vmcnt(0)" ::: "memory");
    __syncthreads();
    bf16x8 af[4], bfr[4];
    #pragma unroll
    for (int i = 0; i < 4; i++)
      af[i] = *(const bf16x8*)(As + (wm * 64 + i * 16 + lr) * 32 + lk * 8);
    #pragma unroll
    for (int j = 0; j < 4; j++)
      bfr[j] = *(const bf16x8*)(Bs + (wn * 64 + j * 16 + lr) * 32 + lk * 8);
    #pragma unroll
    for (int i = 0; i < 4; i++)
      #pragma unroll
      for (int j = 0; j < 4; j++)
        acc[i][j] = __builtin_amdgcn_mfma_f32_16x16x32_bf16(af[i], bfr[j], acc[i][j], 0, 0, 0);
  }

  const int rb = (lane >> 4) * 4, cl = lane & 15;
  #pragma unroll
  for (int i = 0; i < 4; i++){
    #pragma unroll
    for (int j = 0; j < 4; j++){
      const int mb = m0 + wm * 64 + i * 16 + rb;
      const int n  = n0 + wn * 64 + j * 16 + cl;
      if (!qside && n >= 1024){            // V^T packed x4 along s
        int n1 = n - 1024, h = n1 >> 7, d = n1 & 127, b = mb >> 11, s = mb & 2047;
        u32 lo = (u32)f2b(acc[i][j][0]) | ((u32)f2b(acc[i][j][1]) << 16);
        u32 hi = (u32)f2b(acc[i][j][2]) | ((u32)f2b(acc[i][j][3]) << 16);
        *(uint2*)(vt + (((size_t)(b * 16 + h) * 128 + d) * 2048 + s)) = make_uint2(lo, hi);
      } else {
        #pragma unroll
        for (int r = 0; r < 4; r++){
          int m = mb + r;
          float v = acc[i][j][r];
          if (qside){
            if (n < 1024){
              qrp[(size_t)m * 1024 + n] = f2b(v);
            } else {
              int n1 = n - 1024, h = n1 >> 6, d = n1 & 63;
              qbuf[(((size_t)(m >> 11) * 16 + h) * 2048 + (m & 2047)) * 128 + d] = f2b(v * QSCALE);
            }
          } else {                        // kv-side, n < 1024: k_c scatter
            int h = n >> 6, d = n & 63;
            kbuf[(((size_t)(m >> 11) * 16 + h) * 2048 + (m & 2047)) * 128 + d] = f2b(v);
          }
        }
      }
    }
  }
}

// ---------------- RoPE: rotate q_r/k_r halves into q/k dims [64,128) ----------------
__global__ void rope_k(const u16* __restrict__ qrp, const u16* __restrict__ dcat,
                       u16* __restrict__ Qb, u16* __restrict__ Kb){
  int idx = blockIdx.x * 256 + threadIdx.x;         // 2*2048*16*32 = 2^21
  if (idx >= (1 << 21)) return;
  int j = idx & 31, h = (idx >> 5) & 15, s = (idx >> 9) & 2047, b = (idx >> 20) & 1;
  float inv = exp2f((float)j * (-13.287712379549449f / 32.0f));
  float ang = (float)s * inv;
  float sn = sinf(ang), cs = cosf(ang);
  size_t soq = ((size_t)(b * 2048 + s)) * 1024 + h * 64 + j;
  size_t sok = ((size_t)(b * 2048 + s)) * 1536 + 512 + h * 64 + j;
  size_t dd = (((size_t)(b * 16 + h)) * 2048 + s) * 128;
  {
    float x1 = b2f(qrp[soq]), x2 = b2f(qrp[soq + 32]);
    Qb[dd + 64 + j] = f2b((x1 * cs - x2 * sn) * QSCALE);
    Qb[dd + 96 + j] = f2b((x1 * sn + x2 * cs) * QSCALE);
  }
  {
    float x1 = b2f(dcat[sok]), x2 = b2f(dcat[sok + 32]);
    Kb[dd + 64 + j] = f2b(x1 * cs - x2 * sn);
    Kb[dd + 96 + j] = f2b(x1 * sn + x2 * cs);
  }
}

// ---------------- flash partial: 8-wave QBLK=256, k-window split (z halves) ----------------
// grid (32 bh, 8 pp, 2 z); qt = 7-pp (heavy first). Block covers tiles [z*T, (z+1)*T),
// T = 2qt+2. Writes UNNORMALIZED O^T (bf16, token-major) + per-row (m,l) fp32.
// R14: defer-max (T13, THR=8) — rescale only when lane-local max drifts above base+8.
__global__ __launch_bounds__(512, 1)
void flash_part(const u16* __restrict__ Q, const u16* __restrict__ K,
                const u16* __restrict__ VT, u16* __restrict__ Op0,
                u16* __restrict__ Op1, float2* __restrict__ ML){
  __shared__ u16 k_s[3][8192];   // [64 k][128 d] per buf, 256B rows, col16 ^= row&15
  __shared__ u16 v_s[8192];      // [128 d][64 k], 128B rows, col16 ^= d&7
  __shared__ u16 p_s[8][2048];   // per-wave [32 q][64 k], u16 ^= (q&7)<<3
  const int tid = threadIdx.x;
  const int w = tid >> 6, l = tid & 63;
  const int lr = l & 15, hk = l >> 4;
  const int bh = blockIdx.x;
  const int qt = 7 - blockIdx.y;
  const int z  = blockIdx.z;
  const int b = bh >> 4, h = bh & 15;
  const size_t base = (size_t)bh * 2048 * 128;
  const u16* Qb = Q + base;
  const u16* Kb = K + base;
  const u16* Vb = VT + base;
  u16* myp = p_s[w];
  const int q0 = qt * 256 + w * 32;
  const int T  = 2 * qt + 2;          // periods in this half-window
  const int t0 = z * T;               // absolute start tile

  bf16x8 qa[2][4];
  #pragma unroll
  for (int mi = 0; mi < 2; mi++)
    #pragma unroll
    for (int ks = 0; ks < 4; ks++)
      qa[mi][ks] = *(const bf16x8*)(Qb + (size_t)(q0 + mi * 16 + lr) * 128 + ks * 32 + hk * 8);

  f32x4 o[2][8] = {};                 // o[mi][dj][r] = O^T[d=dj*16+hk*4+r][q=q0+mi*16+lr]
  float mbase[2] = {-1e30f, -1e30f};
  float lsum[2] = {0.f, 0.f};

  auto STAGE_K = [&](int kt, int buf){
    #pragma unroll
    for (int it = 0; it < 2; ++it){
      int row = it * 32 + w * 4 + (l >> 4);
      gload16(Kb + (size_t)(kt * 64 + row) * 128 + (((l & 15) ^ (row & 15)) << 3),
              &k_s[buf][it * 4096 + w * 512]);
    }
  };
  auto STAGE_V = [&](int kt){
    #pragma unroll
    for (int it = 0; it < 2; ++it){
      int d = it * 64 + w * 8 + (l >> 3);
      gload16(Vb + (size_t)d * 2048 + kt * 64 + (((l & 7) ^ (d & 7)) << 3),
              &v_s[it * 4096 + w * 512]);
    }
  };

  // prologue: K(t0)->buf0, K(t0+1)->buf1; wait K(t0) only (K(t0+1) rides on).
  STAGE_K(t0, 0);
  STAGE_K(t0 + 1, 1);
  asm volatile("s_waitcnt vmcnt(2)" ::: "memory");
  __builtin_amdgcn_s_barrier();

  for (int tt = 0; tt < T; ++tt){
    const int t = t0 + tt;              // absolute tile
    STAGE_V(t);                         // issue V(t) first (FIFO age matters)
    const bool pre2 = (tt + 2 < T);
    if (pre2) STAGE_K(t + 2, (tt + 2) % 3);

    const bool act = (t * 64 <= q0 + 31);
    if (act){
      const u16* ks_ = k_s[tt % 3];
      // ---- S^T = K Q^T (64 k-rows x 32 q-cols per wave) ----
      f32x4 sc[2][4] = {};
      #pragma unroll
      for (int ksd = 0; ksd < 4; ++ksd){
        bf16x8 kb[4];
        #pragma unroll
        for (int nj = 0; nj < 4; ++nj){
          int row = nj * 16 + lr;
          kb[nj] = *(const bf16x8*)(ks_ + row * 128 + (((ksd * 4 + hk) ^ lr) << 3));
        }
        __builtin_amdgcn_s_setprio(1);
        #pragma unroll
        for (int mi = 0; mi < 2; ++mi)
          #pragma unroll
          for (int nj = 0; nj < 4; ++nj)
            sc[mi][nj] = __builtin_amdgcn_mfma_f32_16x16x32_bf16(kb[nj], qa[mi][ksd], sc[mi][nj], 0, 0, 0);
        __builtin_amdgcn_s_setprio(0);
      }
      // ---- mask (diagonal tiles only) + lane-local max ----
      float lmax[2] = {-3e38f, -3e38f};
      if (t * 64 + 63 > q0){
        #pragma unroll
        for (int mi = 0; mi < 2; ++mi){
          int qrow = q0 + mi * 16 + lr;
          #pragma unroll
          for (int nj = 0; nj < 4; ++nj)
            #pragma unroll
            for (int r = 0; r < 4; ++r){
              int kc = t * 64 + nj * 16 + hk * 4 + r;
              float s = (kc <= qrow) ? sc[mi][nj][r] : -1e30f;
              sc[mi][nj][r] = s;
              lmax[mi] = fmaxf(lmax[mi], s);
            }
        }
      } else {
        #pragma unroll
        for (int mi = 0; mi < 2; ++mi)
          #pragma unroll
          for (int nj = 0; nj < 4; ++nj)
            #pragma unroll
            for (int r = 0; r < 4; ++r)
              lmax[mi] = fmaxf(lmax[mi], sc[mi][nj][r]);
      }
      // ---- defer-max (T13, THR=8): rescale only when base drifts; shuffles on rare path ----
      if (__any((lmax[0] > mbase[0] + 8.f) || (lmax[1] > mbase[1] + 8.f))){
        #pragma unroll
        for (int mi = 0; mi < 2; ++mi){
          float mx = lmax[mi];
          mx = fmaxf(mx, __shfl_xor(mx, 16));
          mx = fmaxf(mx, __shfl_xor(mx, 32));
          float mnew = fmaxf(mbase[mi], mx);
          float alpha = exp2f(mbase[mi] - mnew);
          mbase[mi] = mnew;
          lsum[mi] *= alpha;
          #pragma unroll
          for (int dj = 0; dj < 8; ++dj)
            #pragma unroll
            for (int r = 0; r < 4; ++r) o[mi][dj][r] *= alpha;
        }
      }
      // ---- P = exp2(S - base): lane-local sum, f2b packed writes ----
      #pragma unroll
      for (int mi = 0; mi < 2; ++mi){
        u16* prow = myp + (mi * 16 + lr) * 64;
        float rs = 0.f;
        #pragma unroll
        for (int nj = 0; nj < 4; ++nj){
          float p0 = exp2f(sc[mi][nj][0] - mbase[mi]);
          float p1 = exp2f(sc[mi][nj][1] - mbase[mi]);
          float p2 = exp2f(sc[mi][nj][2] - mbase[mi]);
          float p3 = exp2f(sc[mi][nj][3] - mbase[mi]);
          rs += (p0 + p1) + (p2 + p3);
          u32 a = (u32)f2b(p0) | ((u32)f2b(p1) << 16);
          u32 c = (u32)f2b(p2) | ((u32)f2b(p3) << 16);
          *(uint2*)(prow + ((nj * 16 + hk * 4) ^ ((lr & 7) << 3))) = make_uint2(a, c);
        }
        lsum[mi] += rs;
      }
    }

    // ---- counted wait: V(t) + K(t+1) landed; K(t+2) stays in flight across barriers ----
    if (pre2) asm volatile("s_waitcnt vmcnt(2)" ::: "memory");
    else      asm volatile("s_waitcnt vmcnt(0)" ::: "memory");
    __builtin_amdgcn_s_barrier();
    asm volatile("s_waitcnt lgkmcnt(0)" ::: "memory");   // own P writes visible
    __builtin_amdgcn_sched_barrier(0);

    if (act){
      // ---- O^T += V^T P^T ----
      #pragma unroll
      for (int kk = 0; kk < 2; ++kk){
        bf16x8 pb[2], va[8];
        #pragma unroll
        for (int mi = 0; mi < 2; ++mi)
          pb[mi] = *(const bf16x8*)(myp + (mi * 16 + lr) * 64 +
                     ((kk * 32 + hk * 8) ^ ((lr & 7) << 3)));
        #pragma unroll
        for (int dj = 0; dj < 8; ++dj){
          int d = dj * 16 + lr;
          va[dj] = *(const bf16x8*)(&v_s[d * 64 + (((kk * 4 + hk) ^ (lr & 7)) << 3)]);
        }
        __builtin_amdgcn_s_setprio(1);
        #pragma unroll
        for (int mi = 0; mi < 2; ++mi)
          #pragma unroll
          for (int dj = 0; dj < 8; ++dj)
            o[mi][dj] = __builtin_amdgcn_mfma_f32_16x16x32_bf16(va[dj], pb[mi], o[mi][dj], 0, 0, 0);
        __builtin_amdgcn_s_setprio(0);
      }
    }

    __builtin_amdgcn_s_barrier();    // all PV reads of v_s done before next STAGE_V
  }

  // ---- epilogue: reduce l across hk; store (m,l); write UNNORMALIZED O^T partial ----
  u16* Op = z ? Op1 : Op0;
  u16* scr = myp;                    // 16 q x 128 d per mi round (4 KB, wave-private)
  #pragma unroll
  for (int mi = 0; mi < 2; ++mi){
    float lt = lsum[mi];
    lt += __shfl_xor(lt, 16);
    lt += __shfl_xor(lt, 32);
    if (hk == 0){
      float2 v; v.x = mbase[mi]; v.y = lt;
      ML[((size_t)z * 32 + bh) * 2048 + qt * 256 + w * 32 + mi * 16 + lr] = v;
    }
    #pragma unroll
    for (int dj = 0; dj < 8; ++dj){
      u32 a = (u32)f2b(o[mi][dj][0]) | ((u32)f2b(o[mi][dj][1]) << 16);
      u32 c = (u32)f2b(o[mi][dj][2]) | ((u32)f2b(o[mi][dj][3]) << 16);
      *(uint2*)(scr + lr * 128 + ((dj * 16 + hk * 4) ^ ((lr & 7) << 3))) = make_uint2(a, c);
    }
    asm volatile("s_waitcnt lgkmcnt(0)" ::: "memory");
    __builtin_amdgcn_sched_barrier(0);
    #pragma unroll
    for (int rr = 0; rr < 4; ++rr){
      int row = rr * 4 + hk;
      uint4 vv = *(const uint4*)(scr + row * 128 + ((lr * 8) ^ ((row & 7) << 3)));
      *(uint4*)(Op + ((size_t)(b * 2048) + qt * 256 + w * 32 + mi * 16 + row) * 2048
                    + h * 128 + lr * 8) = vv;
    }
    asm volatile("s_waitcnt lgkmcnt(0)" ::: "memory");   // reads done before next mi overwrite
    __builtin_amdgcn_sched_barrier(0);
  }
}

// ---------------- merge two k-halves: O = (O0*w0 + O1*w1) / (l0*w0 + l1*w1) ----------------
__global__ void merge_k(const u16* __restrict__ Op0, const u16* __restrict__ Op1,
                        const float2* __restrict__ ML, u16* __restrict__ Y){
  int i = blockIdx.x * 256 + threadIdx.x;      // 8 cols per thread: 4096*2048/8 = 2^20
  if (i >= (1 << 20)) return;
  int row = i >> 8;                            // token row (b*2048+s)
  int c8 = (i & 255) << 3;                     // col group
  int b = row >> 11, s = row & 2047, h = c8 >> 7;
  int bh = b * 16 + h;
  float2 ml0 = ML[(size_t)bh * 2048 + s];
  float2 ml1 = ML[(size_t)(32 + bh) * 2048 + s];
  float m = fmaxf(ml0.x, ml1.x);
  float w0 = exp2f(ml0.x - m), w1 = exp2f(ml1.x - m);
  float inv = 1.0f / fmaxf(ml0.y * w0 + ml1.y * w1, 1e-30f);
  size_t off = (size_t)row * 2048 + c8;
  uint4 a = *(const uint4*)(Op0 + off);
  uint4 c = *(const uint4*)(Op1 + off);
  u32 res[4];
  u32 au[4] = {a.x, a.y, a.z, a.w};
  u32 cu[4] = {c.x, c.y, c.z, c.w};
  #pragma unroll
  for (int j = 0; j < 4; ++j){
    float2 f = up2(au[j]), g = up2(cu[j]);
    float r0 = (f.x * w0 + g.x * w1) * inv;
    float r1 = (f.y * w0 + g.y * w1) * inv;
    res[j] = (u32)f2b(r0) | ((u32)f2b(r1) << 16);
  }
  *(uint4*)(Y + off) = make_uint4(res[0], res[1], res[2], res[3]);
}

// ---------------------------------------------------------------------------
extern "C" void kernel_launch(void* const* d_in, const int* in_sizes, int n_in,
                              void* d_out, int out_size, void* d_ws, size_t ws_size,
                              hipStream_t stream){
  u16* p = (u16*)d_ws;
  auto alloc = [&](size_t n){ u16* r = p; p += n; return r; };
  // contiguous bf16 weights: [W_kv_d | W_q_d | W_rope_k | W_rope_q | W_q_u | W_k_u | W_v_u | W_o]
  u16* wcat = alloc(8650752);
  u16* downW  = wcat;                 // 1536 x 2048
  u16* qcatW  = wcat + 3145728;       // 2048 x 256 (rope_q, q_u)
  u16* kvcatW = wcat + 3670016;       // 3072 x 256 (k_u, v_u)
  u16* wo     = wcat + 4456448;       // 2048 x 2048
  u16* xb   = alloc(8388608);         // (4096, 2048) bf16; REUSED as Opart0 after rope
  u16* dcat = alloc(6291456);         // (4096, 1536); dcat+qrp REUSED as Opart1 after rope
  u16* qrp  = alloc(4194304);         // (4096, 1024) q_r pre-rope
  u16* qbuf = alloc(8388608);         // (B,NH,S,128)
  u16* kbuf = alloc(8388608);
  u16* vt   = alloc(8388608);         // (B,NH,128,S)
  u16* ybuf = alloc(8388608);         // (4096, 2048)
  float2* ml = (float2*)alloc(524288);  // [2][32][2048] (m,l) = 1 MiB

  CSrc cs;
  cs.s[0] = (const float*)d_in[0];   // x
  cs.s[1] = (const float*)d_in[1];   // W_kv_d
  cs.s[2] = (const float*)d_in[2];   // W_q_d
  cs.s[3] = (const float*)d_in[6];   // W_rope_k
  cs.s[4] = (const float*)d_in[7];   // W_rope_q
  cs.s[5] = (const float*)d_in[4];   // W_q_u
  cs.s[6] = (const float*)d_in[3];   // W_k_u
  cs.s[7] = (const float*)d_in[5];   // W_v_u
  cs.s[8] = (const float*)d_in[8];   // W_o
  cvt_all<<<16640, 256, 0, stream>>>(cs, xb, wcat);

  dim3 blk(256);
  // down-projections fused: dcat = x @ [W_kv_d|W_q_d|W_rope_k]^T   (384 blocks, swizzled)
  gemm_bt<0><<<dim3(12, 32), blk, 0, stream>>>(xb, 2048, downW, dcat, 1536, 2048);
  // up-projections fused (q-side + kv-side), 1280 blocks, swizzled
  gemm_up<<<dim3(40, 32), blk, 0, stream>>>(dcat, qcatW, kvcatW, qbuf, qrp, kbuf, vt);
  // rope into q/k dims [64,128) (q pre-scaled by QSCALE incl. log2e)
  rope_k<<<(1 << 21) / 256, 256, 0, stream>>>(qrp, dcat, qbuf, kbuf);
  // attention partials: xb/dcat/qrp are dead -> reuse as partial-O buffers
  u16* op0 = xb;                      // 8388608 u16 = one full (4096,2048) bf16
  u16* op1 = dcat;                    // dcat+qrp contiguous = 10485760 u16 >= 8388608
  flash_part<<<dim3(32, 8, 2), dim3(512), 0, stream>>>(qbuf, kbuf, vt, op0, op1, ml);
  // merge halves -> ybuf
  merge_k<<<4096, 256, 0, stream>>>(op0, op1, ml, ybuf);
  // output projection (fp32 out), 512 blocks, swizzled
  gemm_bt<3><<<dim3(16, 32), blk, 0, stream>>>(ybuf, 2048, wo, d_out, 2048, 2048);
}

// Round 15
// 211.600 us; speedup vs baseline: 1.1104x; 1.0112x over previous
//
#include <hip/hip_runtime.h>

typedef unsigned short u16;
typedef unsigned int u32;
typedef __attribute__((ext_vector_type(8))) short bf16x8;
typedef __attribute__((ext_vector_type(4))) float f32x4;

#define DEVI static __device__ __forceinline__

DEVI u16 f2b(float f){
  u32 x = __float_as_uint(f);
  return (u16)((x + 0x7fffu + ((x >> 16) & 1u)) >> 16);   // RNE bf16
}
DEVI float b2f(u16 u){ return __uint_as_float(((u32)u) << 16); }
DEVI float2 up2(u32 u){   // packed bf16 pair -> floats (low u16 = first elem)
  return make_float2(__uint_as_float(u << 16), __uint_as_float(u & 0xffff0000u));
}
DEVI u32 pk2(float a, float b){   // cheap round-half-up bf16 pack (P is >=0, finite)
  u32 ua = __float_as_uint(a) + 0x8000u;
  u32 ub = __float_as_uint(b) + 0x8000u;
  return (ua >> 16) | (ub & 0xffff0000u);
}
DEVI void gload16(const u16* g, u16* l){
  __builtin_amdgcn_global_load_lds((const __attribute__((address_space(1))) void*)g,
                                   (__attribute__((address_space(3))) void*)l,
                                   16, 0, 0);
}

// qscale' = (1/sqrt(128)) * log2(e): scores land in base-2 units -> exp2f softmax
#define QSCALE 0.12751744900929456f

// ---------------- fused fp32 -> bf16 convert: x + all 8 weights (one launch) ----------------
struct CSrc { const float* s[9]; };
__global__ void cvt_all(CSrc cs, u16* __restrict__ xb, u16* __restrict__ wcat){
  int i = blockIdx.x * 256 + threadIdx.x;     // float4 index; 2097152 + 2162688 total
  if (i >= 4259840) return;
  const float4* s; int lo, di; uint2* d;
  if (i < 2097152){
    s = (const float4*)cs.s[0]; lo = 0; di = i; d = (uint2*)xb;
  } else {
    int j = i - 2097152; di = j; d = (uint2*)wcat;
    if      (j <  131072){ s = (const float4*)cs.s[1]; lo = 0;       }
    else if (j <  262144){ s = (const float4*)cs.s[2]; lo = 131072;  }
    else if (j <  786432){ s = (const float4*)cs.s[3]; lo = 262144;  }
    else if (j <  851968){ s = (const float4*)cs.s[4]; lo = 786432;  }
    else if (j <  917504){ s = (const float4*)cs.s[5]; lo = 851968;  }
    else if (j <  983040){ s = (const float4*)cs.s[6]; lo = 917504;  }
    else if (j < 1114112){ s = (const float4*)cs.s[7]; lo = 983040;  }
    else                 { s = (const float4*)cs.s[8]; lo = 1114112; }
  }
  float4 f = s[di - lo];
  u32 a = (u32)f2b(f.x) | ((u32)f2b(f.y) << 16);
  u32 b = (u32)f2b(f.z) | ((u32)f2b(f.w) << 16);
  d[di] = make_uint2(a, b);
}

// ---------------- MFMA bf16 GEMM:  C[M,N] = A[M,K] * W[N,K]^T ----------------
// MODE 0: bf16 row-major ld=N     MODE 3: fp32 row-major
template<int MODE>
__global__ __launch_bounds__(256, 2)
void gemm_bt(const u16* __restrict__ A, int lda, const u16* __restrict__ W,
             void* __restrict__ D, int N, int K){
  __shared__ u16 As[128 * 32];
  __shared__ u16 Bs[128 * 32];
  const int tid = threadIdx.x;
  const int wave = tid >> 6, lane = tid & 63;
  const int lr = lane & 15, lk = lane >> 4;
  int bid = blockIdx.y * gridDim.x + blockIdx.x;
  const int nwg = gridDim.x * gridDim.y;
  bid = (bid & 7) * (nwg >> 3) + (bid >> 3);          // XCD-contiguous remap
  const int bx = bid % gridDim.x, by = bid / gridDim.x;
  const int m0 = by * 128, n0 = bx * 128;
  const int wm = wave >> 1, wn = wave & 1;
  f32x4 acc[4][4] = {};

  const u16* a0 = A + (size_t)(m0 + (tid >> 2)) * lda + (tid & 3) * 8;
  const u16* a1 = a0 + (size_t)64 * lda;
  const u16* b0 = W + (size_t)(n0 + (tid >> 2)) * K + (tid & 3) * 8;
  const u16* b1 = b0 + (size_t)64 * K;
  u16* lA0 = As + wave * 512;  u16* lA1 = As + 2048 + wave * 512;
  u16* lB0 = Bs + wave * 512;  u16* lB1 = Bs + 2048 + wave * 512;

  for (int k0 = 0; k0 < K; k0 += 32){
    __syncthreads();
    gload16(a0 + k0, lA0);
    gload16(a1 + k0, lA1);
    gload16(b0 + k0, lB0);
    gload16(b1 + k0, lB1);
    asm volatile("s_waitcnt vmcnt(0)" ::: "memory");
    __syncthreads();
    bf16x8 af[4], bfr[4];
    #pragma unroll
    for (int i = 0; i < 4; i++)
      af[i] = *(const bf16x8*)(As + (wm * 64 + i * 16 + lr) * 32 + lk * 8);
    #pragma unroll
    for (int j = 0; j < 4; j++)
      bfr[j] = *(const bf16x8*)(Bs + (wn * 64 + j * 16 + lr) * 32 + lk * 8);
    #pragma unroll
    for (int i = 0; i < 4; i++)
      #pragma unroll
      for (int j = 0; j < 4; j++)
        acc[i][j] = __builtin_amdgcn_mfma_f32_16x16x32_bf16(af[i], bfr[j], acc[i][j], 0, 0, 0);
  }

  const int rb = (lane >> 4) * 4, cl = lane & 15;
  #pragma unroll
  for (int i = 0; i < 4; i++){
    #pragma unroll
    for (int j = 0; j < 4; j++){
      const int mb = m0 + wm * 64 + i * 16 + rb;
      const int n  = n0 + wn * 64 + j * 16 + cl;
      #pragma unroll
      for (int r = 0; r < 4; r++){
        int m = mb + r;
        float v = acc[i][j][r];
        if (MODE == 0) ((u16*)D)[(size_t)m * N + n] = f2b(v);
        else           ((float*)D)[(size_t)m * N + n] = v;
      }
    }
  }
}

// ---------------- fused up-projections (K=256, lda=1536), one launch ----------------
__global__ __launch_bounds__(256, 2)
void gemm_up(const u16* __restrict__ dcat, const u16* __restrict__ qW,
             const u16* __restrict__ kvW, u16* __restrict__ qbuf,
             u16* __restrict__ qrp, u16* __restrict__ kbuf, u16* __restrict__ vt){
  __shared__ u16 As[128 * 32];
  __shared__ u16 Bs[128 * 32];
  const int tid = threadIdx.x;
  const int wave = tid >> 6, lane = tid & 63;
  const int lr = lane & 15, lk = lane >> 4;
  int bid = blockIdx.y * 40 + blockIdx.x;
  bid = (bid & 7) * 160 + (bid >> 3);                 // XCD-contiguous remap (1280/8)
  const int bx = bid % 40, by = bid / 40;
  const bool qside = bx < 16;
  const u16* A = qside ? dcat + 256 : dcat;
  const u16* W = qside ? qW : kvW;
  const int n0 = (qside ? bx : bx - 16) * 128;
  const int m0 = by * 128;
  const int wm = wave >> 1, wn = wave & 1;
  f32x4 acc[4][4] = {};

  const u16* a0 = A + (size_t)(m0 + (tid >> 2)) * 1536 + (tid & 3) * 8;
  const u16* a1 = a0 + (size_t)64 * 1536;
  const u16* b0 = W + (size_t)(n0 + (tid >> 2)) * 256 + (tid & 3) * 8;
  const u16* b1 = b0 + (size_t)64 * 256;
  u16* lA0 = As + wave * 512;  u16* lA1 = As + 2048 + wave * 512;
  u16* lB0 = Bs + wave * 512;  u16* lB1 = Bs + 2048 + wave * 512;

  for (int k0 = 0; k0 < 256; k0 += 32){
    __syncthreads();
    gload16(a0 + k0, lA0);
    gload16(a1 + k0, lA1);
    gload16(b0 + k0, lB0);
    gload16(b1 + k0, lB1);
    asm volatile("s_waitcnt vmcnt(0)" ::: "memory");
    __syncthreads();
    bf16x8 af[4], bfr[4];
    #pragma unroll
    for (int i = 0; i < 4; i++)
      af[i] = *(const bf16x8*)(As + (wm * 64 + i * 16 + lr) * 32 + lk * 8);
    #pragma unroll
    for (int j = 0; j < 4; j++)
      bfr[j] = *(const bf16x8*)(Bs + (wn * 64 + j * 16 + lr) * 32 + lk * 8);
    #pragma unroll
    for (int i = 0; i < 4; i++)
      #pragma unroll
      for (int j = 0; j < 4; j++)
        acc[i][j] = __builtin_amdgcn_mfma_f32_16x16x32_bf16(af[i], bfr[j], acc[i][j], 0, 0, 0);
  }

  const int rb = (lane >> 4) * 4, cl = lane & 15;
  #pragma unroll
  for (int i = 0; i < 4; i++){
    #pragma unroll
    for (int j = 0; j < 4; j++){
      const int mb = m0 + wm * 64 + i * 16 + rb;
      const int n  = n0 + wn * 64 + j * 16 + cl;
      if (!qside && n >= 1024){            // V^T packed x4 along s
        int n1 = n - 1024, h = n1 >> 7, d = n1 & 127, b = mb >> 11, s = mb & 2047;
        u32 lo = (u32)f2b(acc[i][j][0]) | ((u32)f2b(acc[i][j][1]) << 16);
        u32 hi = (u32)f2b(acc[i][j][2]) | ((u32)f2b(acc[i][j][3]) << 16);
        *(uint2*)(vt + (((size_t)(b * 16 + h) * 128 + d) * 2048 + s)) = make_uint2(lo, hi);
      } else {
        #pragma unroll
        for (int r = 0; r < 4; r++){
          int m = mb + r;
          float v = acc[i][j][r];
          if (qside){
            if (n < 1024){
              qrp[(size_t)m * 1024 + n] = f2b(v);
            } else {
              int n1 = n - 1024, h = n1 >> 6, d = n1 & 63;
              qbuf[(((size_t)(m >> 11) * 16 + h) * 2048 + (m & 2047)) * 128 + d] = f2b(v * QSCALE);
            }
          } else {                        // kv-side, n < 1024: k_c scatter
            int h = n >> 6, d = n & 63;
            kbuf[(((size_t)(m >> 11) * 16 + h) * 2048 + (m & 2047)) * 128 + d] = f2b(v);
          }
        }
      }
    }
  }
}

// ---------------- RoPE: rotate q_r/k_r halves into q/k dims [64,128) ----------------
__global__ void rope_k(const u16* __restrict__ qrp, const u16* __restrict__ dcat,
                       u16* __restrict__ Qb, u16* __restrict__ Kb){
  int idx = blockIdx.x * 256 + threadIdx.x;         // 2*2048*16*32 = 2^21
  if (idx >= (1 << 21)) return;
  int j = idx & 31, h = (idx >> 5) & 15, s = (idx >> 9) & 2047, b = (idx >> 20) & 1;
  float inv = exp2f((float)j * (-13.287712379549449f / 32.0f));
  float ang = (float)s * inv;
  float sn = sinf(ang), cs = cosf(ang);
  size_t soq = ((size_t)(b * 2048 + s)) * 1024 + h * 64 + j;
  size_t sok = ((size_t)(b * 2048 + s)) * 1536 + 512 + h * 64 + j;
  size_t dd = (((size_t)(b * 16 + h)) * 2048 + s) * 128;
  {
    float x1 = b2f(qrp[soq]), x2 = b2f(qrp[soq + 32]);
    Qb[dd + 64 + j] = f2b((x1 * cs - x2 * sn) * QSCALE);
    Qb[dd + 96 + j] = f2b((x1 * sn + x2 * cs) * QSCALE);
  }
  {
    float x1 = b2f(dcat[sok]), x2 = b2f(dcat[sok + 32]);
    Kb[dd + 64 + j] = f2b(x1 * cs - x2 * sn);
    Kb[dd + 96 + j] = f2b(x1 * sn + x2 * cs);
  }
}

// ---------------- flash partial: 8-wave QBLK=256, k-split, SINGLE-barrier pipeline ----------------
// grid (32 bh, 8 pp, 2 z); qt = 7-pp. Block covers tiles [z*T, (z+1)*T), T = 2qt+2.
// K and V both triple-buffered; ONE barrier per tile; counted vmcnt(4) never-drain.
// Safety: every LDS buffer's {read(t), write(t+3 -> same buf)} pair straddles >=1 barrier.
// R15: cheap pk2 P-pack (round-half-up) replaces f2b pairs in the hot path.
__global__ __launch_bounds__(512, 1)
void flash_part(const u16* __restrict__ Q, const u16* __restrict__ K,
                const u16* __restrict__ VT, u16* __restrict__ Op0,
                u16* __restrict__ Op1, float2* __restrict__ ML){
  __shared__ u16 k_s[3][8192];   // [64 k][128 d] per buf, 256B rows, col16 ^= row&15
  __shared__ u16 v_s[3][8192];   // [128 d][64 k] per buf, 128B rows, col16 ^= d&7
  __shared__ u16 p_s[8][2048];   // per-wave [32 q][64 k], u16 ^= (q&7)<<3
  const int tid = threadIdx.x;
  const int w = tid >> 6, l = tid & 63;
  const int lr = l & 15, hk = l >> 4;
  const int bh = blockIdx.x;
  const int qt = 7 - blockIdx.y;
  const int z  = blockIdx.z;
  const int b = bh >> 4, h = bh & 15;
  const size_t base = (size_t)bh * 2048 * 128;
  const u16* Qb = Q + base;
  const u16* Kb = K + base;
  const u16* Vb = VT + base;
  u16* myp = p_s[w];
  const int q0 = qt * 256 + w * 32;
  const int T  = 2 * qt + 2;          // periods in this half-window
  const int t0 = z * T;               // absolute start tile

  bf16x8 qa[2][4];
  #pragma unroll
  for (int mi = 0; mi < 2; mi++)
    #pragma unroll
    for (int ks = 0; ks < 4; ks++)
      qa[mi][ks] = *(const bf16x8*)(Qb + (size_t)(q0 + mi * 16 + lr) * 128 + ks * 32 + hk * 8);

  f32x4 o[2][8] = {};                 // o[mi][dj][r] = O^T[d=dj*16+hk*4+r][q=q0+mi*16+lr]
  float mbase[2] = {-1e30f, -1e30f};
  float lsum[2] = {0.f, 0.f};

  auto STAGE_K = [&](int kt, int buf){
    #pragma unroll
    for (int it = 0; it < 2; ++it){
      int row = it * 32 + w * 4 + (l >> 4);
      gload16(Kb + (size_t)(kt * 64 + row) * 128 + (((l & 15) ^ (row & 15)) << 3),
              &k_s[buf][it * 4096 + w * 512]);
    }
  };
  auto STAGE_V = [&](int kt, int buf){
    #pragma unroll
    for (int it = 0; it < 2; ++it){
      int d = it * 64 + w * 8 + (l >> 3);
      gload16(Vb + (size_t)d * 2048 + kt * 64 + (((l & 7) ^ (d & 7)) << 3),
              &v_s[buf][it * 4096 + w * 512]);
    }
  };

  // prologue: V(t0),K(t0) landed before loop; K(t0+1) rides on (counted).
  STAGE_V(t0, 0);
  STAGE_K(t0, 0);
  STAGE_K(t0 + 1, 1);
  asm volatile("s_waitcnt vmcnt(2)" ::: "memory");
  __builtin_amdgcn_s_barrier();

  for (int tt = 0; tt < T; ++tt){
    const int t = t0 + tt;               // absolute tile
    const bool preV = (tt + 1 < T);
    const bool preK = (tt + 2 < T);
    if (preV) STAGE_V(t + 1, (tt + 1) % 3);   // issue V(t+1) first (FIFO age)
    if (preK) STAGE_K(t + 2, (tt + 2) % 3);

    const bool act = (t * 64 <= q0 + 31);
    if (act){
      const u16* ks_ = k_s[tt % 3];
      // ---- S^T = K Q^T (64 k-rows x 32 q-cols per wave) ----
      f32x4 sc[2][4] = {};
      #pragma unroll
      for (int ksd = 0; ksd < 4; ++ksd){
        bf16x8 kb[4];
        #pragma unroll
        for (int nj = 0; nj < 4; ++nj){
          int row = nj * 16 + lr;
          kb[nj] = *(const bf16x8*)(ks_ + row * 128 + (((ksd * 4 + hk) ^ lr) << 3));
        }
        __builtin_amdgcn_s_setprio(1);
        #pragma unroll
        for (int mi = 0; mi < 2; ++mi)
          #pragma unroll
          for (int nj = 0; nj < 4; ++nj)
            sc[mi][nj] = __builtin_amdgcn_mfma_f32_16x16x32_bf16(kb[nj], qa[mi][ksd], sc[mi][nj], 0, 0, 0);
        __builtin_amdgcn_s_setprio(0);
      }
      // ---- mask (diagonal tiles only) + lane-local max ----
      float lmax[2] = {-3e38f, -3e38f};
      if (t * 64 + 63 > q0){
        #pragma unroll
        for (int mi = 0; mi < 2; ++mi){
          int qrow = q0 + mi * 16 + lr;
          #pragma unroll
          for (int nj = 0; nj < 4; ++nj)
            #pragma unroll
            for (int r = 0; r < 4; ++r){
              int kc = t * 64 + nj * 16 + hk * 4 + r;
              float s = (kc <= qrow) ? sc[mi][nj][r] : -1e30f;
              sc[mi][nj][r] = s;
              lmax[mi] = fmaxf(lmax[mi], s);
            }
        }
      } else {
        #pragma unroll
        for (int mi = 0; mi < 2; ++mi)
          #pragma unroll
          for (int nj = 0; nj < 4; ++nj)
            #pragma unroll
            for (int r = 0; r < 4; ++r)
              lmax[mi] = fmaxf(lmax[mi], sc[mi][nj][r]);
      }
      // ---- defer-max (T13, THR=8): rescale only on drift; shuffles on rare path ----
      if (__any((lmax[0] > mbase[0] + 8.f) || (lmax[1] > mbase[1] + 8.f))){
        #pragma unroll
        for (int mi = 0; mi < 2; ++mi){
          float mx = lmax[mi];
          mx = fmaxf(mx, __shfl_xor(mx, 16));
          mx = fmaxf(mx, __shfl_xor(mx, 32));
          float mnew = fmaxf(mbase[mi], mx);
          float alpha = exp2f(mbase[mi] - mnew);
          mbase[mi] = mnew;
          lsum[mi] *= alpha;
          #pragma unroll
          for (int dj = 0; dj < 8; ++dj)
            #pragma unroll
            for (int r = 0; r < 4; ++r) o[mi][dj][r] *= alpha;
        }
      }
      // ---- P = exp2(S - base): lane-local sum, cheap pk2 packed writes ----
      #pragma unroll
      for (int mi = 0; mi < 2; ++mi){
        u16* prow = myp + (mi * 16 + lr) * 64;
        float rs = 0.f;
        #pragma unroll
        for (int nj = 0; nj < 4; ++nj){
          float p0 = exp2f(sc[mi][nj][0] - mbase[mi]);
          float p1 = exp2f(sc[mi][nj][1] - mbase[mi]);
          float p2 = exp2f(sc[mi][nj][2] - mbase[mi]);
          float p3 = exp2f(sc[mi][nj][3] - mbase[mi]);
          rs += (p0 + p1) + (p2 + p3);
          *(uint2*)(prow + ((nj * 16 + hk * 4) ^ ((lr & 7) << 3))) =
              make_uint2(pk2(p0, p1), pk2(p2, p3));
        }
        lsum[mi] += rs;
      }
    }

    // ---- counted wait: V(t)+K(t+1) landed; V(t+1)+K(t+2) stay in flight ----
    if (preK)      asm volatile("s_waitcnt vmcnt(4)" ::: "memory");
    else if (preV) asm volatile("s_waitcnt vmcnt(2)" ::: "memory");
    else           asm volatile("s_waitcnt vmcnt(0)" ::: "memory");
    __builtin_amdgcn_s_barrier();                        // ONE barrier per tile
    asm volatile("s_waitcnt lgkmcnt(0)" ::: "memory");   // own P writes visible
    __builtin_amdgcn_sched_barrier(0);

    if (act){
      // ---- O^T += V^T P^T ----
      const u16* vs_ = v_s[tt % 3];
      #pragma unroll
      for (int kk = 0; kk < 2; ++kk){
        bf16x8 pb[2], va[8];
        #pragma unroll
        for (int mi = 0; mi < 2; ++mi)
          pb[mi] = *(const bf16x8*)(myp + (mi * 16 + lr) * 64 +
                     ((kk * 32 + hk * 8) ^ ((lr & 7) << 3)));
        #pragma unroll
        for (int dj = 0; dj < 8; ++dj){
          int d = dj * 16 + lr;
          va[dj] = *(const bf16x8*)(vs_ + d * 64 + (((kk * 4 + hk) ^ (lr & 7)) << 3));
        }
        __builtin_amdgcn_s_setprio(1);
        #pragma unroll
        for (int mi = 0; mi < 2; ++mi)
          #pragma unroll
          for (int dj = 0; dj < 8; ++dj)
            o[mi][dj] = __builtin_amdgcn_mfma_f32_16x16x32_bf16(va[dj], pb[mi], o[mi][dj], 0, 0, 0);
        __builtin_amdgcn_s_setprio(0);
      }
    }
    // no trailing barrier: V/K triple-buffers guarantee write(t+3) vs read(t) separation
  }

  // ---- epilogue: reduce l across hk; store (m,l); write UNNORMALIZED O^T partial ----
  u16* Op = z ? Op1 : Op0;
  u16* scr = myp;                    // wave-private 4 KB scratch
  #pragma unroll
  for (int mi = 0; mi < 2; ++mi){
    float lt = lsum[mi];
    lt += __shfl_xor(lt, 16);
    lt += __shfl_xor(lt, 32);
    if (hk == 0){
      float2 v; v.x = mbase[mi]; v.y = lt;
      ML[((size_t)z * 32 + bh) * 2048 + qt * 256 + w * 32 + mi * 16 + lr] = v;
    }
    #pragma unroll
    for (int dj = 0; dj < 8; ++dj){
      u32 a = (u32)f2b(o[mi][dj][0]) | ((u32)f2b(o[mi][dj][1]) << 16);
      u32 c = (u32)f2b(o[mi][dj][2]) | ((u32)f2b(o[mi][dj][3]) << 16);
      *(uint2*)(scr + lr * 128 + ((dj * 16 + hk * 4) ^ ((lr & 7) << 3))) = make_uint2(a, c);
    }
    asm volatile("s_waitcnt lgkmcnt(0)" ::: "memory");
    __builtin_amdgcn_sched_barrier(0);
    #pragma unroll
    for (int rr = 0; rr < 4; ++rr){
      int row = rr * 4 + hk;
      uint4 vv = *(const uint4*)(scr + row * 128 + ((lr * 8) ^ ((row & 7) << 3)));
      *(uint4*)(Op + ((size_t)(b * 2048) + qt * 256 + w * 32 + mi * 16 + row) * 2048
                    + h * 128 + lr * 8) = vv;
    }
    asm volatile("s_waitcnt lgkmcnt(0)" ::: "memory");   // reads done before next mi overwrite
    __builtin_amdgcn_sched_barrier(0);
  }
}

// ---------------- merge two k-halves: O = (O0*w0 + O1*w1) / (l0*w0 + l1*w1) ----------------
__global__ void merge_k(const u16* __restrict__ Op0, const u16* __restrict__ Op1,
                        const float2* __restrict__ ML, u16* __restrict__ Y){
  int i = blockIdx.x * 256 + threadIdx.x;      // 8 cols per thread: 4096*2048/8 = 2^20
  if (i >= (1 << 20)) return;
  int row = i >> 8;                            // token row (b*2048+s)
  int c8 = (i & 255) << 3;                     // col group
  int b = row >> 11, s = row & 2047, h = c8 >> 7;
  int bh = b * 16 + h;
  float2 ml0 = ML[(size_t)bh * 2048 + s];
  float2 ml1 = ML[(size_t)(32 + bh) * 2048 + s];
  float m = fmaxf(ml0.x, ml1.x);
  float w0 = exp2f(ml0.x - m), w1 = exp2f(ml1.x - m);
  float inv = 1.0f / fmaxf(ml0.y * w0 + ml1.y * w1, 1e-30f);
  size_t off = (size_t)row * 2048 + c8;
  uint4 a = *(const uint4*)(Op0 + off);
  uint4 c = *(const uint4*)(Op1 + off);
  u32 res[4];
  u32 au[4] = {a.x, a.y, a.z, a.w};
  u32 cu[4] = {c.x, c.y, c.z, c.w};
  #pragma unroll
  for (int j = 0; j < 4; ++j){
    float2 f = up2(au[j]), g = up2(cu[j]);
    float r0 = (f.x * w0 + g.x * w1) * inv;
    float r1 = (f.y * w0 + g.y * w1) * inv;
    res[j] = (u32)f2b(r0) | ((u32)f2b(r1) << 16);
  }
  *(uint4*)(Y + off) = make_uint4(res[0], res[1], res[2], res[3]);
}

// ---------------------------------------------------------------------------
extern "C" void kernel_launch(void* const* d_in, const int* in_sizes, int n_in,
                              void* d_out, int out_size, void* d_ws, size_t ws_size,
                              hipStream_t stream){
  u16* p = (u16*)d_ws;
  auto alloc = [&](size_t n){ u16* r = p; p += n; return r; };
  // contiguous bf16 weights: [W_kv_d | W_q_d | W_rope_k | W_rope_q | W_q_u | W_k_u | W_v_u | W_o]
  u16* wcat = alloc(8650752);
  u16* downW  = wcat;                 // 1536 x 2048
  u16* qcatW  = wcat + 3145728;       // 2048 x 256 (rope_q, q_u)
  u16* kvcatW = wcat + 3670016;       // 3072 x 256 (k_u, v_u)
  u16* wo     = wcat + 4456448;       // 2048 x 2048
  u16* xb   = alloc(8388608);         // (4096, 2048) bf16; REUSED as Opart0 after rope
  u16* dcat = alloc(6291456);         // (4096, 1536); dcat+qrp REUSED as Opart1 after rope
  u16* qrp  = alloc(4194304);         // (4096, 1024) q_r pre-rope
  u16* qbuf = alloc(8388608);         // (B,NH,S,128)
  u16* kbuf = alloc(8388608);
  u16* vt   = alloc(8388608);         // (B,NH,128,S)
  u16* ybuf = alloc(8388608);         // (4096, 2048)
  float2* ml = (float2*)alloc(524288);  // [2][32][2048] (m,l) = 1 MiB

  CSrc cs;
  cs.s[0] = (const float*)d_in[0];   // x
  cs.s[1] = (const float*)d_in[1];   // W_kv_d
  cs.s[2] = (const float*)d_in[2];   // W_q_d
  cs.s[3] = (const float*)d_in[6];   // W_rope_k
  cs.s[4] = (const float*)d_in[7];   // W_rope_q
  cs.s[5] = (const float*)d_in[4];   // W_q_u
  cs.s[6] = (const float*)d_in[3];   // W_k_u
  cs.s[7] = (const float*)d_in[5];   // W_v_u
  cs.s[8] = (const float*)d_in[8];   // W_o
  cvt_all<<<16640, 256, 0, stream>>>(cs, xb, wcat);

  dim3 blk(256);
  // down-projections fused: dcat = x @ [W_kv_d|W_q_d|W_rope_k]^T   (384 blocks, swizzled)
  gemm_bt<0><<<dim3(12, 32), blk, 0, stream>>>(xb, 2048, downW, dcat, 1536, 2048);
  // up-projections fused (q-side + kv-side), 1280 blocks, swizzled
  gemm_up<<<dim3(40, 32), blk, 0, stream>>>(dcat, qcatW, kvcatW, qbuf, qrp, kbuf, vt);
  // rope into q/k dims [64,128) (q pre-scaled by QSCALE incl. log2e)
  rope_k<<<(1 << 21) / 256, 256, 0, stream>>>(qrp, dcat, qbuf, kbuf);
  // attention partials: xb/dcat/qrp are dead -> reuse as partial-O buffers
  u16* op0 = xb;                      // 8388608 u16 = one full (4096,2048) bf16
  u16* op1 = dcat;                    // dcat+qrp contiguous = 10485760 u16 >= 8388608
  flash_part<<<dim3(32, 8, 2), dim3(512), 0, stream>>>(qbuf, kbuf, vt, op0, op1, ml);
  // merge halves -> ybuf
  merge_k<<<4096, 256, 0, stream>>>(op0, op1, ml, ybuf);
  // output projection (fp32 out), 512 blocks, swizzled
  gemm_bt<3><<<dim3(16, 32), blk, 0, stream>>>(ybuf, 2048, wo, d_out, 2048, 2048);
}

// Round 16
// 196.622 us; speedup vs baseline: 1.1949x; 1.0762x over previous
//
#include <hip/hip_runtime.h>

typedef unsigned short u16;
typedef unsigned int u32;
typedef __attribute__((ext_vector_type(8))) short bf16x8;
typedef __attribute__((ext_vector_type(4))) float f32x4;

#define DEVI static __device__ __forceinline__

DEVI u16 f2b(float f){
  u32 x = __float_as_uint(f);
  return (u16)((x + 0x7fffu + ((x >> 16) & 1u)) >> 16);   // RNE bf16
}
DEVI float b2f(u16 u){ return __uint_as_float(((u32)u) << 16); }
DEVI float2 up2(u32 u){   // packed bf16 pair -> floats (low u16 = first elem)
  return make_float2(__uint_as_float(u << 16), __uint_as_float(u & 0xffff0000u));
}
DEVI u32 pk2(float a, float b){   // cheap round-half-up bf16 pack (P is >=0, finite)
  u32 ua = __float_as_uint(a) + 0x8000u;
  u32 ub = __float_as_uint(b) + 0x8000u;
  return (ua >> 16) | (ub & 0xffff0000u);
}
DEVI void gload16(const u16* g, u16* l){
  __builtin_amdgcn_global_load_lds((const __attribute__((address_space(1))) void*)g,
                                   (__attribute__((address_space(3))) void*)l,
                                   16, 0, 0);
}

// qscale' = (1/sqrt(128)) * log2(e): scores land in base-2 units -> exp2f softmax
#define QSCALE 0.12751744900929456f

// ---------------- fused fp32 -> bf16 convert: x + all 8 weights (one launch) ----------------
struct CSrc { const float* s[9]; };
__global__ void cvt_all(CSrc cs, u16* __restrict__ xb, u16* __restrict__ wcat){
  int i = blockIdx.x * 256 + threadIdx.x;     // float4 index; 2097152 + 2162688 total
  if (i >= 4259840) return;
  const float4* s; int lo, di; uint2* d;
  if (i < 2097152){
    s = (const float4*)cs.s[0]; lo = 0; di = i; d = (uint2*)xb;
  } else {
    int j = i - 2097152; di = j; d = (uint2*)wcat;
    if      (j <  131072){ s = (const float4*)cs.s[1]; lo = 0;       }
    else if (j <  262144){ s = (const float4*)cs.s[2]; lo = 131072;  }
    else if (j <  786432){ s = (const float4*)cs.s[3]; lo = 262144;  }
    else if (j <  851968){ s = (const float4*)cs.s[4]; lo = 786432;  }
    else if (j <  917504){ s = (const float4*)cs.s[5]; lo = 851968;  }
    else if (j <  983040){ s = (const float4*)cs.s[6]; lo = 917504;  }
    else if (j < 1114112){ s = (const float4*)cs.s[7]; lo = 983040;  }
    else                 { s = (const float4*)cs.s[8]; lo = 1114112; }
  }
  float4 f = s[di - lo];
  u32 a = (u32)f2b(f.x) | ((u32)f2b(f.y) << 16);
  u32 b = (u32)f2b(f.z) | ((u32)f2b(f.w) << 16);
  d[di] = make_uint2(a, b);
}

// ---------------- MFMA bf16 GEMM, BK=64 + XOR-swizzled LDS:  C = A * W^T ----------------
// MODE 0: bf16 row-major ld=N     MODE 3: fp32 row-major
// LDS [128][64] linear dest (gload lane x 16B), global source col pre-swizzled by
// granule g ^= row&7; fragment reads apply the same involution -> conflict-free b128.
template<int MODE>
__global__ __launch_bounds__(256, 2)
void gemm_bt(const u16* __restrict__ A, int lda, const u16* __restrict__ W,
             void* __restrict__ D, int N, int K){
  __shared__ u16 As[128 * 64];   // 16 KB
  __shared__ u16 Bs[128 * 64];   // 16 KB
  const int tid = threadIdx.x;
  const int wave = tid >> 6, lane = tid & 63;
  const int lr = lane & 15, lk = lane >> 4;
  int bid = blockIdx.y * gridDim.x + blockIdx.x;
  const int nwg = gridDim.x * gridDim.y;
  bid = (bid & 7) * (nwg >> 3) + (bid >> 3);          // XCD-contiguous remap
  const int bx = bid % gridDim.x, by = bid / gridDim.x;
  const int m0 = by * 128, n0 = bx * 128;
  const int wm = wave >> 1, wn = wave & 1;
  f32x4 acc[4][4] = {};

  // staging: sweep s in 0..3, rows s*32 + tid>>3, src col granule (tid&7) ^ (row&7)
  const int srow = tid >> 3;                       // 0..31 (row&7 == srow&7? rows s*32+srow, s*32%8==0)
  const int scol = ((tid & 7) ^ (srow & 7)) << 3;  // pre-swizzled global col offset
  const u16* ag = A + (size_t)(m0 + srow) * lda + scol;
  const u16* bg = W + (size_t)(n0 + srow) * K + scol;
  u16* lA = As + wave * 512;                       // wave-uniform dest; HW adds lane*16B
  u16* lB = Bs + wave * 512;

  for (int k0 = 0; k0 < K; k0 += 64){
    __syncthreads();
    #pragma unroll
    for (int s = 0; s < 4; ++s){
      gload16(ag + (size_t)s * 32 * lda + k0, lA + s * 2048);
      gload16(bg + (size_t)s * 32 * K   + k0, lB + s * 2048);
    }
    asm volatile("s_waitcnt vmcnt(0)" ::: "memory");
    __syncthreads();
    #pragma unroll
    for (int ks = 0; ks < 2; ++ks){
      bf16x8 af[4], bfr[4];
      const int perm = ((ks * 4 + lk) ^ (lr & 7)) << 3;
      #pragma unroll
      for (int i = 0; i < 4; i++)
        af[i] = *(const bf16x8*)(As + (wm * 64 + i * 16 + lr) * 64 + perm);
      #pragma unroll
      for (int j = 0; j < 4; j++)
        bfr[j] = *(const bf16x8*)(Bs + (wn * 64 + j * 16 + lr) * 64 + perm);
      #pragma unroll
      for (int i = 0; i < 4; i++)
        #pragma unroll
        for (int j = 0; j < 4; j++)
          acc[i][j] = __builtin_amdgcn_mfma_f32_16x16x32_bf16(af[i], bfr[j], acc[i][j], 0, 0, 0);
    }
  }

  const int rb = (lane >> 4) * 4, cl = lane & 15;
  #pragma unroll
  for (int i = 0; i < 4; i++){
    #pragma unroll
    for (int j = 0; j < 4; j++){
      const int mb = m0 + wm * 64 + i * 16 + rb;
      const int n  = n0 + wn * 64 + j * 16 + cl;
      #pragma unroll
      for (int r = 0; r < 4; r++){
        int m = mb + r;
        float v = acc[i][j][r];
        if (MODE == 0) ((u16*)D)[(size_t)m * N + n] = f2b(v);
        else           ((float*)D)[(size_t)m * N + n] = v;
      }
    }
  }
}

// ---------------- fused up-projections (K=256, lda=1536), one launch ----------------
__global__ __launch_bounds__(256, 2)
void gemm_up(const u16* __restrict__ dcat, const u16* __restrict__ qW,
             const u16* __restrict__ kvW, u16* __restrict__ qbuf,
             u16* __restrict__ qrp, u16* __restrict__ kbuf, u16* __restrict__ vt){
  __shared__ u16 As[128 * 32];
  __shared__ u16 Bs[128 * 32];
  const int tid = threadIdx.x;
  const int wave = tid >> 6, lane = tid & 63;
  const int lr = lane & 15, lk = lane >> 4;
  int bid = blockIdx.y * 40 + blockIdx.x;
  bid = (bid & 7) * 160 + (bid >> 3);                 // XCD-contiguous remap (1280/8)
  const int bx = bid % 40, by = bid / 40;
  const bool qside = bx < 16;
  const u16* A = qside ? dcat + 256 : dcat;
  const u16* W = qside ? qW : kvW;
  const int n0 = (qside ? bx : bx - 16) * 128;
  const int m0 = by * 128;
  const int wm = wave >> 1, wn = wave & 1;
  f32x4 acc[4][4] = {};

  const u16* a0 = A + (size_t)(m0 + (tid >> 2)) * 1536 + (tid & 3) * 8;
  const u16* a1 = a0 + (size_t)64 * 1536;
  const u16* b0 = W + (size_t)(n0 + (tid >> 2)) * 256 + (tid & 3) * 8;
  const u16* b1 = b0 + (size_t)64 * 256;
  u16* lA0 = As + wave * 512;  u16* lA1 = As + 2048 + wave * 512;
  u16* lB0 = Bs + wave * 512;  u16* lB1 = Bs + 2048 + wave * 512;

  for (int k0 = 0; k0 < 256; k0 += 32){
    __syncthreads();
    gload16(a0 + k0, lA0);
    gload16(a1 + k0, lA1);
    gload16(b0 + k0, lB0);
    gload16(b1 + k0, lB1);
    asm volatile("s_waitcnt vmcnt(0)" ::: "memory");
    __syncthreads();
    bf16x8 af[4], bfr[4];
    #pragma unroll
    for (int i = 0; i < 4; i++)
      af[i] = *(const bf16x8*)(As + (wm * 64 + i * 16 + lr) * 32 + lk * 8);
    #pragma unroll
    for (int j = 0; j < 4; j++)
      bfr[j] = *(const bf16x8*)(Bs + (wn * 64 + j * 16 + lr) * 32 + lk * 8);
    #pragma unroll
    for (int i = 0; i < 4; i++)
      #pragma unroll
      for (int j = 0; j < 4; j++)
        acc[i][j] = __builtin_amdgcn_mfma_f32_16x16x32_bf16(af[i], bfr[j], acc[i][j], 0, 0, 0);
  }

  const int rb = (lane >> 4) * 4, cl = lane & 15;
  #pragma unroll
  for (int i = 0; i < 4; i++){
    #pragma unroll
    for (int j = 0; j < 4; j++){
      const int mb = m0 + wm * 64 + i * 16 + rb;
      const int n  = n0 + wn * 64 + j * 16 + cl;
      if (!qside && n >= 1024){            // V^T packed x4 along s
        int n1 = n - 1024, h = n1 >> 7, d = n1 & 127, b = mb >> 11, s = mb & 2047;
        u32 lo = (u32)f2b(acc[i][j][0]) | ((u32)f2b(acc[i][j][1]) << 16);
        u32 hi = (u32)f2b(acc[i][j][2]) | ((u32)f2b(acc[i][j][3]) << 16);
        *(uint2*)(vt + (((size_t)(b * 16 + h) * 128 + d) * 2048 + s)) = make_uint2(lo, hi);
      } else {
        #pragma unroll
        for (int r = 0; r < 4; r++){
          int m = mb + r;
          float v = acc[i][j][r];
          if (qside){
            if (n < 1024){
              qrp[(size_t)m * 1024 + n] = f2b(v);
            } else {
              int n1 = n - 1024, h = n1 >> 6, d = n1 & 63;
              qbuf[(((size_t)(m >> 11) * 16 + h) * 2048 + (m & 2047)) * 128 + d] = f2b(v * QSCALE);
            }
          } else {                        // kv-side, n < 1024: k_c scatter
            int h = n >> 6, d = n & 63;
            kbuf[(((size_t)(m >> 11) * 16 + h) * 2048 + (m & 2047)) * 128 + d] = f2b(v);
          }
        }
      }
    }
  }
}

// ---------------- RoPE: rotate q_r/k_r halves into q/k dims [64,128) ----------------
__global__ void rope_k(const u16* __restrict__ qrp, const u16* __restrict__ dcat,
                       u16* __restrict__ Qb, u16* __restrict__ Kb){
  int idx = blockIdx.x * 256 + threadIdx.x;         // 2*2048*16*32 = 2^21
  if (idx >= (1 << 21)) return;
  int j = idx & 31, h = (idx >> 5) & 15, s = (idx >> 9) & 2047, b = (idx >> 20) & 1;
  float inv = exp2f((float)j * (-13.287712379549449f / 32.0f));
  float ang = (float)s * inv;
  float sn = sinf(ang), cs = cosf(ang);
  size_t soq = ((size_t)(b * 2048 + s)) * 1024 + h * 64 + j;
  size_t sok = ((size_t)(b * 2048 + s)) * 1536 + 512 + h * 64 + j;
  size_t dd = (((size_t)(b * 16 + h)) * 2048 + s) * 128;
  {
    float x1 = b2f(qrp[soq]), x2 = b2f(qrp[soq + 32]);
    Qb[dd + 64 + j] = f2b((x1 * cs - x2 * sn) * QSCALE);
    Qb[dd + 96 + j] = f2b((x1 * sn + x2 * cs) * QSCALE);
  }
  {
    float x1 = b2f(dcat[sok]), x2 = b2f(dcat[sok + 32]);
    Kb[dd + 64 + j] = f2b(x1 * cs - x2 * sn);
    Kb[dd + 96 + j] = f2b(x1 * sn + x2 * cs);
  }
}

// ---------------- flash partial: 8-wave QBLK=256, k-split, SINGLE-barrier pipeline ----------------
// grid (32 bh, 8 pp, 2 z); qt = 7-pp. Block covers tiles [z*T, (z+1)*T), T = 2qt+2.
// K and V both triple-buffered; ONE barrier per tile; counted vmcnt(4) never-drain.
__global__ __launch_bounds__(512, 1)
void flash_part(const u16* __restrict__ Q, const u16* __restrict__ K,
                const u16* __restrict__ VT, u16* __restrict__ Op0,
                u16* __restrict__ Op1, float2* __restrict__ ML){
  __shared__ u16 k_s[3][8192];   // [64 k][128 d] per buf, 256B rows, col16 ^= row&15
  __shared__ u16 v_s[3][8192];   // [128 d][64 k] per buf, 128B rows, col16 ^= d&7
  __shared__ u16 p_s[8][2048];   // per-wave [32 q][64 k], u16 ^= (q&7)<<3
  const int tid = threadIdx.x;
  const int w = tid >> 6, l = tid & 63;
  const int lr = l & 15, hk = l >> 4;
  const int bh = blockIdx.x;
  const int qt = 7 - blockIdx.y;
  const int z  = blockIdx.z;
  const int b = bh >> 4, h = bh & 15;
  const size_t base = (size_t)bh * 2048 * 128;
  const u16* Qb = Q + base;
  const u16* Kb = K + base;
  const u16* Vb = VT + base;
  u16* myp = p_s[w];
  const int q0 = qt * 256 + w * 32;
  const int T  = 2 * qt + 2;          // periods in this half-window
  const int t0 = z * T;               // absolute start tile

  bf16x8 qa[2][4];
  #pragma unroll
  for (int mi = 0; mi < 2; mi++)
    #pragma unroll
    for (int ks = 0; ks < 4; ks++)
      qa[mi][ks] = *(const bf16x8*)(Qb + (size_t)(q0 + mi * 16 + lr) * 128 + ks * 32 + hk * 8);

  f32x4 o[2][8] = {};                 // o[mi][dj][r] = O^T[d=dj*16+hk*4+r][q=q0+mi*16+lr]
  float mbase[2] = {-1e30f, -1e30f};
  float lsum[2] = {0.f, 0.f};

  auto STAGE_K = [&](int kt, int buf){
    #pragma unroll
    for (int it = 0; it < 2; ++it){
      int row = it * 32 + w * 4 + (l >> 4);
      gload16(Kb + (size_t)(kt * 64 + row) * 128 + (((l & 15) ^ (row & 15)) << 3),
              &k_s[buf][it * 4096 + w * 512]);
    }
  };
  auto STAGE_V = [&](int kt, int buf){
    #pragma unroll
    for (int it = 0; it < 2; ++it){
      int d = it * 64 + w * 8 + (l >> 3);
      gload16(Vb + (size_t)d * 2048 + kt * 64 + (((l & 7) ^ (d & 7)) << 3),
              &v_s[buf][it * 4096 + w * 512]);
    }
  };

  // prologue: V(t0),K(t0) landed before loop; K(t0+1) rides on (counted).
  STAGE_V(t0, 0);
  STAGE_K(t0, 0);
  STAGE_K(t0 + 1, 1);
  asm volatile("s_waitcnt vmcnt(2)" ::: "memory");
  __builtin_amdgcn_s_barrier();

  for (int tt = 0; tt < T; ++tt){
    const int t = t0 + tt;               // absolute tile
    const bool preV = (tt + 1 < T);
    const bool preK = (tt + 2 < T);
    if (preV) STAGE_V(t + 1, (tt + 1) % 3);   // issue V(t+1) first (FIFO age)
    if (preK) STAGE_K(t + 2, (tt + 2) % 3);

    const bool act = (t * 64 <= q0 + 31);
    if (act){
      const u16* ks_ = k_s[tt % 3];
      // ---- S^T = K Q^T (64 k-rows x 32 q-cols per wave) ----
      f32x4 sc[2][4] = {};
      #pragma unroll
      for (int ksd = 0; ksd < 4; ++ksd){
        bf16x8 kb[4];
        #pragma unroll
        for (int nj = 0; nj < 4; ++nj){
          int row = nj * 16 + lr;
          kb[nj] = *(const bf16x8*)(ks_ + row * 128 + (((ksd * 4 + hk) ^ lr) << 3));
        }
        __builtin_amdgcn_s_setprio(1);
        #pragma unroll
        for (int mi = 0; mi < 2; ++mi)
          #pragma unroll
          for (int nj = 0; nj < 4; ++nj)
            sc[mi][nj] = __builtin_amdgcn_mfma_f32_16x16x32_bf16(kb[nj], qa[mi][ksd], sc[mi][nj], 0, 0, 0);
        __builtin_amdgcn_s_setprio(0);
      }
      // ---- mask (diagonal tiles only) + lane-local max ----
      float lmax[2] = {-3e38f, -3e38f};
      if (t * 64 + 63 > q0){
        #pragma unroll
        for (int mi = 0; mi < 2; ++mi){
          int qrow = q0 + mi * 16 + lr;
          #pragma unroll
          for (int nj = 0; nj < 4; ++nj)
            #pragma unroll
            for (int r = 0; r < 4; ++r){
              int kc = t * 64 + nj * 16 + hk * 4 + r;
              float s = (kc <= qrow) ? sc[mi][nj][r] : -1e30f;
              sc[mi][nj][r] = s;
              lmax[mi] = fmaxf(lmax[mi], s);
            }
        }
      } else {
        #pragma unroll
        for (int mi = 0; mi < 2; ++mi)
          #pragma unroll
          for (int nj = 0; nj < 4; ++nj)
            #pragma unroll
            for (int r = 0; r < 4; ++r)
              lmax[mi] = fmaxf(lmax[mi], sc[mi][nj][r]);
      }
      // ---- defer-max (T13, THR=8): rescale only on drift; shuffles on rare path ----
      if (__any((lmax[0] > mbase[0] + 8.f) || (lmax[1] > mbase[1] + 8.f))){
        #pragma unroll
        for (int mi = 0; mi < 2; ++mi){
          float mx = lmax[mi];
          mx = fmaxf(mx, __shfl_xor(mx, 16));
          mx = fmaxf(mx, __shfl_xor(mx, 32));
          float mnew = fmaxf(mbase[mi], mx);
          float alpha = exp2f(mbase[mi] - mnew);
          mbase[mi] = mnew;
          lsum[mi] *= alpha;
          #pragma unroll
          for (int dj = 0; dj < 8; ++dj)
            #pragma unroll
            for (int r = 0; r < 4; ++r) o[mi][dj][r] *= alpha;
        }
      }
      // ---- P = exp2(S - base): lane-local sum, cheap pk2 packed writes ----
      #pragma unroll
      for (int mi = 0; mi < 2; ++mi){
        u16* prow = myp + (mi * 16 + lr) * 64;
        float rs = 0.f;
        #pragma unroll
        for (int nj = 0; nj < 4; ++nj){
          float p0 = exp2f(sc[mi][nj][0] - mbase[mi]);
          float p1 = exp2f(sc[mi][nj][1] - mbase[mi]);
          float p2 = exp2f(sc[mi][nj][2] - mbase[mi]);
          float p3 = exp2f(sc[mi][nj][3] - mbase[mi]);
          rs += (p0 + p1) + (p2 + p3);
          *(uint2*)(prow + ((nj * 16 + hk * 4) ^ ((lr & 7) << 3))) =
              make_uint2(pk2(p0, p1), pk2(p2, p3));
        }
        lsum[mi] += rs;
      }
    }

    // ---- counted wait: V(t)+K(t+1) landed; V(t+1)+K(t+2) stay in flight ----
    if (preK)      asm volatile("s_waitcnt vmcnt(4)" ::: "memory");
    else if (preV) asm volatile("s_waitcnt vmcnt(2)" ::: "memory");
    else           asm volatile("s_waitcnt vmcnt(0)" ::: "memory");
    __builtin_amdgcn_s_barrier();                        // ONE barrier per tile
    asm volatile("s_waitcnt lgkmcnt(0)" ::: "memory");   // own P writes visible
    __builtin_amdgcn_sched_barrier(0);

    if (act){
      // ---- O^T += V^T P^T ----
      const u16* vs_ = v_s[tt % 3];
      #pragma unroll
      for (int kk = 0; kk < 2; ++kk){
        bf16x8 pb[2], va[8];
        #pragma unroll
        for (int mi = 0; mi < 2; ++mi)
          pb[mi] = *(const bf16x8*)(myp + (mi * 16 + lr) * 64 +
                     ((kk * 32 + hk * 8) ^ ((lr & 7) << 3)));
        #pragma unroll
        for (int dj = 0; dj < 8; ++dj){
          int d = dj * 16 + lr;
          va[dj] = *(const bf16x8*)(vs_ + d * 64 + (((kk * 4 + hk) ^ (lr & 7)) << 3));
        }
        __builtin_amdgcn_s_setprio(1);
        #pragma unroll
        for (int mi = 0; mi < 2; ++mi)
          #pragma unroll
          for (int dj = 0; dj < 8; ++dj)
            o[mi][dj] = __builtin_amdgcn_mfma_f32_16x16x32_bf16(va[dj], pb[mi], o[mi][dj], 0, 0, 0);
        __builtin_amdgcn_s_setprio(0);
      }
    }
    // no trailing barrier: V/K triple-buffers guarantee write(t+3) vs read(t) separation
  }

  // ---- epilogue: reduce l across hk; store (m,l); write UNNORMALIZED O^T partial ----
  u16* Op = z ? Op1 : Op0;
  u16* scr = myp;                    // wave-private 4 KB scratch
  #pragma unroll
  for (int mi = 0; mi < 2; ++mi){
    float lt = lsum[mi];
    lt += __shfl_xor(lt, 16);
    lt += __shfl_xor(lt, 32);
    if (hk == 0){
      float2 v; v.x = mbase[mi]; v.y = lt;
      ML[((size_t)z * 32 + bh) * 2048 + qt * 256 + w * 32 + mi * 16 + lr] = v;
    }
    #pragma unroll
    for (int dj = 0; dj < 8; ++dj){
      u32 a = (u32)f2b(o[mi][dj][0]) | ((u32)f2b(o[mi][dj][1]) << 16);
      u32 c = (u32)f2b(o[mi][dj][2]) | ((u32)f2b(o[mi][dj][3]) << 16);
      *(uint2*)(scr + lr * 128 + ((dj * 16 + hk * 4) ^ ((lr & 7) << 3))) = make_uint2(a, c);
    }
    asm volatile("s_waitcnt lgkmcnt(0)" ::: "memory");
    __builtin_amdgcn_sched_barrier(0);
    #pragma unroll
    for (int rr = 0; rr < 4; ++rr){
      int row = rr * 4 + hk;
      uint4 vv = *(const uint4*)(scr + row * 128 + ((lr * 8) ^ ((row & 7) << 3)));
      *(uint4*)(Op + ((size_t)(b * 2048) + qt * 256 + w * 32 + mi * 16 + row) * 2048
                    + h * 128 + lr * 8) = vv;
    }
    asm volatile("s_waitcnt lgkmcnt(0)" ::: "memory");   // reads done before next mi overwrite
    __builtin_amdgcn_sched_barrier(0);
  }
}

// ---------------- merge two k-halves: O = (O0*w0 + O1*w1) / (l0*w0 + l1*w1) ----------------
__global__ void merge_k(const u16* __restrict__ Op0, const u16* __restrict__ Op1,
                        const float2* __restrict__ ML, u16* __restrict__ Y){
  int i = blockIdx.x * 256 + threadIdx.x;      // 8 cols per thread: 4096*2048/8 = 2^20
  if (i >= (1 << 20)) return;
  int row = i >> 8;                            // token row (b*2048+s)
  int c8 = (i & 255) << 3;                     // col group
  int b = row >> 11, s = row & 2047, h = c8 >> 7;
  int bh = b * 16 + h;
  float2 ml0 = ML[(size_t)bh * 2048 + s];
  float2 ml1 = ML[(size_t)(32 + bh) * 2048 + s];
  float m = fmaxf(ml0.x, ml1.x);
  float w0 = exp2f(ml0.x - m), w1 = exp2f(ml1.x - m);
  float inv = 1.0f / fmaxf(ml0.y * w0 + ml1.y * w1, 1e-30f);
  size_t off = (size_t)row * 2048 + c8;
  uint4 a = *(const uint4*)(Op0 + off);
  uint4 c = *(const uint4*)(Op1 + off);
  u32 res[4];
  u32 au[4] = {a.x, a.y, a.z, a.w};
  u32 cu[4] = {c.x, c.y, c.z, c.w};
  #pragma unroll
  for (int j = 0; j < 4; ++j){
    float2 f = up2(au[j]), g = up2(cu[j]);
    float r0 = (f.x * w0 + g.x * w1) * inv;
    float r1 = (f.y * w0 + g.y * w1) * inv;
    res[j] = (u32)f2b(r0) | ((u32)f2b(r1) << 16);
  }
  *(uint4*)(Y + off) = make_uint4(res[0], res[1], res[2], res[3]);
}

// ---------------------------------------------------------------------------
extern "C" void kernel_launch(void* const* d_in, const int* in_sizes, int n_in,
                              void* d_out, int out_size, void* d_ws, size_t ws_size,
                              hipStream_t stream){
  u16* p = (u16*)d_ws;
  auto alloc = [&](size_t n){ u16* r = p; p += n; return r; };
  // contiguous bf16 weights: [W_kv_d | W_q_d | W_rope_k | W_rope_q | W_q_u | W_k_u | W_v_u | W_o]
  u16* wcat = alloc(8650752);
  u16* downW  = wcat;                 // 1536 x 2048
  u16* qcatW  = wcat + 3145728;       // 2048 x 256 (rope_q, q_u)
  u16* kvcatW = wcat + 3670016;       // 3072 x 256 (k_u, v_u)
  u16* wo     = wcat + 4456448;       // 2048 x 2048
  u16* xb   = alloc(8388608);         // (4096, 2048) bf16; REUSED as Opart0 after rope
  u16* dcat = alloc(6291456);         // (4096, 1536); dcat+qrp REUSED as Opart1 after rope
  u16* qrp  = alloc(4194304);         // (4096, 1024) q_r pre-rope
  u16* qbuf = alloc(8388608);         // (B,NH,S,128)
  u16* kbuf = alloc(8388608);
  u16* vt   = alloc(8388608);         // (B,NH,128,S)
  u16* ybuf = alloc(8388608);         // (4096, 2048)
  float2* ml = (float2*)alloc(524288);  // [2][32][2048] (m,l) = 1 MiB

  CSrc cs;
  cs.s[0] = (const float*)d_in[0];   // x
  cs.s[1] = (const float*)d_in[1];   // W_kv_d
  cs.s[2] = (const float*)d_in[2];   // W_q_d
  cs.s[3] = (const float*)d_in[6];   // W_rope_k
  cs.s[4] = (const float*)d_in[7];   // W_rope_q
  cs.s[5] = (const float*)d_in[4];   // W_q_u
  cs.s[6] = (const float*)d_in[3];   // W_k_u
  cs.s[7] = (const float*)d_in[5];   // W_v_u
  cs.s[8] = (const float*)d_in[8];   // W_o
  cvt_all<<<16640, 256, 0, stream>>>(cs, xb, wcat);

  dim3 blk(256);
  // down-projections fused: dcat = x @ [W_kv_d|W_q_d|W_rope_k]^T   (384 blocks, swizzled)
  gemm_bt<0><<<dim3(12, 32), blk, 0, stream>>>(xb, 2048, downW, dcat, 1536, 2048);
  // up-projections fused (q-side + kv-side), 1280 blocks, swizzled
  gemm_up<<<dim3(40, 32), blk, 0, stream>>>(dcat, qcatW, kvcatW, qbuf, qrp, kbuf, vt);
  // rope into q/k dims [64,128) (q pre-scaled by QSCALE incl. log2e)
  rope_k<<<(1 << 21) / 256, 256, 0, stream>>>(qrp, dcat, qbuf, kbuf);
  // attention partials: xb/dcat/qrp are dead -> reuse as partial-O buffers
  u16* op0 = xb;                      // 8388608 u16 = one full (4096,2048) bf16
  u16* op1 = dcat;                    // dcat+qrp contiguous = 10485760 u16 >= 8388608
  flash_part<<<dim3(32, 8, 2), dim3(512), 0, stream>>>(qbuf, kbuf, vt, op0, op1, ml);
  // merge halves -> ybuf
  merge_k<<<4096, 256, 0, stream>>>(op0, op1, ml, ybuf);
  // output projection (fp32 out), 512 blocks, swizzled
  gemm_bt<3><<<dim3(16, 32), blk, 0, stream>>>(ybuf, 2048, wo, d_out, 2048, 2048);
}